// Round 5
// baseline (553.082 us; speedup 1.0000x reference)
//
#include <hip/hip_runtime.h>
#include <hip/hip_bf16.h>
#include <math.h>

#define Bsz 4
#define Tsz 2048
#define Dsz 1024
#define Hn  16
#define HDs 64

typedef __attribute__((ext_vector_type(8))) short bf16x8;
typedef __attribute__((ext_vector_type(4))) float f32x4;

typedef const __attribute__((address_space(1))) void gvoid;
typedef __attribute__((address_space(3))) void lvoid;

__device__ __forceinline__ void async_copy16(const short* g, short* l) {
    __builtin_amdgcn_global_load_lds((gvoid*)g, (lvoid*)l, 16, 0, 0);
}

__device__ __forceinline__ short f2bf(float x) {
    __hip_bfloat16 h = __float2bfloat16(x);
    return *reinterpret_cast<short*>(&h);
}

// pack two fp32 -> two bf16 in one u32 (round-half-up via +0x8000, then
// v_perm grabs the high shorts). lo -> low half, hi -> high half.
__device__ __forceinline__ unsigned int pack_bf16(float hi, float lo) {
    unsigned int uh = __float_as_uint(hi) + 0x8000u;
    unsigned int ul = __float_as_uint(lo) + 0x8000u;
    return __builtin_amdgcn_perm(uh, ul, 0x07060302u);
}

// index into [b, h, t, kc] tensor given m = b*T + t, c = h*64 + kc
__device__ __forceinline__ size_t headed_idx(int m, int c) {
    int b = m >> 11, t = m & 2047, h = c >> 6, kc = c & 63;
    return (((size_t)(b * Hn + h) * Tsz + t) << 6) + kc;
}

// ---------------- LayerNorm: fp32 in, bf16 out -----------------------------
__global__ __launch_bounds__(256) void ln_kernel(const float* __restrict__ x,
                                                 const float* __restrict__ g,
                                                 const float* __restrict__ beta,
                                                 short* __restrict__ out)
{
    const int row = blockIdx.x;
    const float* xr = x + (size_t)row * Dsz;
    float v[4];
    float s = 0.f, s2 = 0.f;
#pragma unroll
    for (int i = 0; i < 4; ++i) {
        v[i] = xr[threadIdx.x + 256 * i];
        s += v[i];
        s2 += v[i] * v[i];
    }
#pragma unroll
    for (int off = 32; off; off >>= 1) {
        s  += __shfl_xor(s,  off);
        s2 += __shfl_xor(s2, off);
    }
    __shared__ float red[8];
    const int wave = threadIdx.x >> 6;
    if ((threadIdx.x & 63) == 0) { red[wave * 2] = s; red[wave * 2 + 1] = s2; }
    __syncthreads();
    s  = red[0] + red[2] + red[4] + red[6];
    s2 = red[1] + red[3] + red[5] + red[7];
    const float mu  = s * (1.f / Dsz);
    const float var = s2 * (1.f / Dsz) - mu * mu;
    const float rs  = rsqrtf(var + 1e-5f);
    short* orow = out + (size_t)row * Dsz;
#pragma unroll
    for (int i = 0; i < 4; ++i) {
        int col = threadIdx.x + 256 * i;
        orow[col] = f2bf((v[i] - mu) * rs * g[col] + beta[col]);
    }
}

// ---------------- fp32 [R][C] slice -> bf16 [C][R] (weight prep) -----------
__global__ __launch_bounds__(256) void transpose_cvt(
    const float* __restrict__ in, short* __restrict__ outp, int R, int C)
{
    __shared__ float tile[32][33];
    const int r0 = blockIdx.y * 32, c0 = blockIdx.x * 32;
    const size_t so = (size_t)blockIdx.z * R * C;
    const int tx = threadIdx.x & 31, ty = threadIdx.x >> 5;
    const float* ip = in + so;
    short* op = outp + so;
#pragma unroll
    for (int i = 0; i < 4; ++i)
        tile[ty + i * 8][tx] = ip[(size_t)(r0 + ty + i * 8) * C + c0 + tx];
    __syncthreads();
#pragma unroll
    for (int i = 0; i < 4; ++i)
        op[(size_t)(c0 + ty + i * 8) * R + r0 + tx] = f2bf(tile[tx][ty + i * 8]);
}

// QKV variant: z 0..47 selects Wq/Wk/Wv head slices, outputs contiguous.
__global__ __launch_bounds__(256) void transpose_cvt_qkv(
    const float* __restrict__ Wq, const float* __restrict__ Wk,
    const float* __restrict__ Wv, short* __restrict__ outp)
{
    __shared__ float tile[32][33];
    const int z = blockIdx.z;
    const float* in = (z < 16) ? Wq : (z < 32) ? Wk : Wv;
    const int zz = z & 15;
    const int r0 = blockIdx.y * 32, c0 = blockIdx.x * 32;
    const int tx = threadIdx.x & 31, ty = threadIdx.x >> 5;
    const float* ip = in + (size_t)zz * (1024 * 64);
    short* op = outp + (size_t)z * (1024 * 64);
#pragma unroll
    for (int i = 0; i < 4; ++i)
        tile[ty + i * 8][tx] = ip[(size_t)(r0 + ty + i * 8) * 64 + c0 + tx];
    __syncthreads();
#pragma unroll
    for (int i = 0; i < 4; ++i)
        op[(size_t)(c0 + ty + i * 8) * 1024 + r0 + tx] = f2bf(tile[tx][ty + i * 8]);
}

// ---------------- bf16 MFMA GEMM, m97 structure ----------------------------
// C[M][N] = A[M][K] (row-major bf16) * Bt[N][K]^T (bf16).
// 128x128 tile, BK=32, 4 waves each computing 64x64 (4x4 of 16x16x32 MFMA).
// v5: XCD-grouped block remap: each XCD owns 8 consecutive m-rows x all
// n-cols (REQUIRES gridDim.y == 64). A-panels disjoint per XCD; active
// K-window per XCD is a few hundred KB << 4MB L2. (FETCH 288->82MB.)
// EPI 0: fused QKV epilogue (N=3072): n<1024 -> Q headed *scale,
//        <2048 -> K headed, else V^T [b,h,kc,t]
// EPI 2: fp32 row-major, + bias + resid
// EPI 3: bf16 row-major, relu(+bias)
template <int EPI>
__global__ __launch_bounds__(256) void gemm_mfma(
    const short* __restrict__ A, const short* __restrict__ Bt,
    const float* __restrict__ bias, const float* __restrict__ resid,
    float* __restrict__ Cf, short* __restrict__ Cb0,
    short* __restrict__ Cb1, short* __restrict__ Cb2,
    int M, int N, int K, float scale)
{
    __shared__ short As[128 * 32];
    __shared__ short Bs[128 * 32];
    const int tid  = threadIdx.x;
    const int lane = tid & 63, wave = tid >> 6;
    const int quad = lane >> 4, l16 = lane & 15;

    // XCD-grouped remap: lin%8 = XCD under round-robin dispatch.
    // XCD owns m-rows [xcd*8, xcd*8+8) x all n. (gridDim.y == 64.)
    const int lin = blockIdx.y * gridDim.x + blockIdx.x;
    const int xcd = lin & 7;
    const int s   = lin >> 3;
    const int my  = xcd * 8 + (s & 7);   // m-row within 64
    const int nx  = s >> 3;              // n-col 0..gridDim.x-1
    const int m0 = my * 128, n0 = nx * 128;

    const int wm = (wave >> 1) * 64, wn = (wave & 1) * 64;

    f32x4 acc[4][4];
#pragma unroll
    for (int i = 0; i < 4; ++i)
#pragma unroll
        for (int j = 0; j < 4; ++j) acc[i][j] = f32x4{0.f, 0.f, 0.f, 0.f};

    const short* gA = A  + (size_t)(m0 + wave * 32 + (lane >> 2)) * K + (lane & 3) * 8;
    const short* gB = Bt + (size_t)(n0 + wave * 32 + (lane >> 2)) * K + (lane & 3) * 8;
    short* lA0 = As + wave * 1024;
    short* lA1 = As + wave * 1024 + 512;
    short* lB0 = Bs + wave * 1024;
    short* lB1 = Bs + wave * 1024 + 512;
    const size_t rstep = (size_t)16 * K;

    for (int k0 = 0; k0 < K; k0 += 32) {
        async_copy16(gA,         lA0);
        async_copy16(gA + rstep, lA1);
        async_copy16(gB,         lB0);
        async_copy16(gB + rstep, lB1);
        gA += 32; gB += 32;
        __syncthreads();
        bf16x8 af[4], bfr[4];
#pragma unroll
        for (int mt = 0; mt < 4; ++mt)
            af[mt] = *(const bf16x8*)(As + (wm + mt * 16 + l16) * 32 + quad * 8);
#pragma unroll
        for (int nt = 0; nt < 4; ++nt)
            bfr[nt] = *(const bf16x8*)(Bs + (wn + nt * 16 + l16) * 32 + quad * 8);
#pragma unroll
        for (int mt = 0; mt < 4; ++mt)
#pragma unroll
            for (int nt = 0; nt < 4; ++nt)
                acc[mt][nt] = __builtin_amdgcn_mfma_f32_16x16x32_bf16(
                    af[mt], bfr[nt], acc[mt][nt], 0, 0, 0);
        __syncthreads();
    }

#pragma unroll
    for (int mt = 0; mt < 4; ++mt) {
#pragma unroll
        for (int nt = 0; nt < 4; ++nt) {
#pragma unroll
            for (int r = 0; r < 4; ++r) {
                const int m = m0 + wm + mt * 16 + quad * 4 + r;
                const int c = n0 + wn + nt * 16 + l16;
                float val = acc[mt][nt][r];
                if (EPI == 0) {
                    const int sel = c >> 10, cl = c & 1023;
                    if (sel == 0)
                        Cb0[headed_idx(m, cl)] = f2bf(val * scale);
                    else if (sel == 1)
                        Cb1[headed_idx(m, cl)] = f2bf(val);
                    else {
                        int b = m >> 11, t = m & 2047;
                        size_t idx = ((((size_t)((b << 4) | (cl >> 6)) << 6) | (cl & 63)) << 11) | t;
                        Cb2[idx] = f2bf(val);
                    }
                } else if (EPI == 2) {
                    size_t idx = (size_t)m * N + c;
                    Cf[idx] = val + bias[c] + resid[idx];
                } else {  // EPI 3
                    float v2 = val + bias[c];
                    Cb0[(size_t)m * N + c] = f2bf(v2 > 0.f ? v2 : 0.f);
                }
            }
        }
    }
}

// ---------------- narrow-N bf16 MFMA GEMM (128x64 tile, BK=64) -------------
// v6: for the two N=1024 GEMMs (proj, FFN2). At 128x128 those have only
// 512 tiles = 2 blocks/CU = 8 waves/CU (round-4: FFN2 at 572 TF, 12% HBM,
// Occupancy 21% -> residency-starved, not BW-bound). 128x64 tile doubles
// the grid to (16,64) = 1024 blocks = 4 blocks/CU = 16 waves/CU; BK=64
// keeps 16 MFMA/wave between barriers (proven m97 density).
//   - LDS [row][64] rows are 128B -> XOR-swizzle granules (g^(row&7)),
//     staged via pre-swizzled global source + linear LDS dest; b128 frag
//     reads then spread 8 lanes per 16B position = optimal for b128.
//   - Same XCD remap: XCD owns 8 m-rows x all 16 n-cols.
// Epilogue = EPI2 (fp32 row-major, + bias + resid). REQUIRES grid (16,64).
__global__ __launch_bounds__(256) void gemm_n64(
    const short* __restrict__ A, const short* __restrict__ Bt,
    const float* __restrict__ bias, const float* __restrict__ resid,
    float* __restrict__ Cf, int M, int N, int K)
{
    __shared__ short As[128 * 64];   // 16 KB
    __shared__ short Bs[64 * 64];    // 8 KB
    const int tid  = threadIdx.x;
    const int lane = tid & 63, wave = tid >> 6;
    const int quad = lane >> 4, l16 = lane & 15;

    const int lin = blockIdx.y * 16 + blockIdx.x;   // grid (16,64)
    const int xcd = lin & 7;
    const int s   = lin >> 3;                       // 0..127
    const int m0  = (xcd * 8 + (s & 7)) * 128;
    const int n0  = (s >> 3) * 64;

    const int wm = (wave >> 1) * 64, wn = (wave & 1) * 32;

    f32x4 acc[4][2];
#pragma unroll
    for (int i = 0; i < 4; ++i)
#pragma unroll
        for (int j = 0; j < 2; ++j) acc[i][j] = f32x4{0.f, 0.f, 0.f, 0.f};

    // staging: A 128x64 shorts = 1024 granules (4/thread), B 64x64 = 512
    // (2/thread). slot sl: row = sl>>3, LDS pos = sl&7, source granule
    // (sl&7)^(row&7) so reads can XOR the same way.
    const short* gA[4];
    const short* gB[2];
    short* lA[4];
    short* lB[2];
#pragma unroll
    for (int i = 0; i < 4; ++i) {
        const int sl = tid + 256 * i, r = sl >> 3, g = (sl & 7) ^ (r & 7);
        gA[i] = A + (size_t)(m0 + r) * K + g * 8;
        lA[i] = As + sl * 8;
    }
#pragma unroll
    for (int i = 0; i < 2; ++i) {
        const int sl = tid + 256 * i, r = sl >> 3, g = (sl & 7) ^ (r & 7);
        gB[i] = Bt + (size_t)(n0 + r) * K + g * 8;
        lB[i] = Bs + sl * 8;
    }

    for (int k0 = 0; k0 < K; k0 += 64) {
#pragma unroll
        for (int i = 0; i < 4; ++i) { async_copy16(gA[i], lA[i]); gA[i] += 64; }
#pragma unroll
        for (int i = 0; i < 2; ++i) { async_copy16(gB[i], lB[i]); gB[i] += 64; }
        __syncthreads();
        bf16x8 af[4][2], bfr[2][2];
#pragma unroll
        for (int mt = 0; mt < 4; ++mt) {
            const int r = wm + mt * 16 + l16;
            af[mt][0] = *(const bf16x8*)(As + r * 64 + (((quad    ) ^ (r & 7)) << 3));
            af[mt][1] = *(const bf16x8*)(As + r * 64 + (((quad + 4) ^ (r & 7)) << 3));
        }
#pragma unroll
        for (int nt = 0; nt < 2; ++nt) {
            const int r = wn + nt * 16 + l16;
            bfr[nt][0] = *(const bf16x8*)(Bs + r * 64 + (((quad    ) ^ (r & 7)) << 3));
            bfr[nt][1] = *(const bf16x8*)(Bs + r * 64 + (((quad + 4) ^ (r & 7)) << 3));
        }
#pragma unroll
        for (int mt = 0; mt < 4; ++mt)
#pragma unroll
            for (int nt = 0; nt < 2; ++nt) {
                acc[mt][nt] = __builtin_amdgcn_mfma_f32_16x16x32_bf16(
                    af[mt][0], bfr[nt][0], acc[mt][nt], 0, 0, 0);
                acc[mt][nt] = __builtin_amdgcn_mfma_f32_16x16x32_bf16(
                    af[mt][1], bfr[nt][1], acc[mt][nt], 0, 0, 0);
            }
        __syncthreads();
    }

#pragma unroll
    for (int mt = 0; mt < 4; ++mt) {
#pragma unroll
        for (int nt = 0; nt < 2; ++nt) {
#pragma unroll
            for (int r = 0; r < 4; ++r) {
                const int m = m0 + wm + mt * 16 + quad * 4 + r;
                const int c = n0 + wn + nt * 16 + l16;
                const size_t idx = (size_t)m * N + c;
                Cf[idx] = acc[mt][nt][r] + bias[c] + resid[idx];
            }
        }
    }
}

// ---------------- MFMA flash attention, LDS-staged K/V ---------------------
// v4: balance + occupancy + L2 residency (round-2 post-mortem: avg 4.8
// waves/CU, 91% stall; FETCH 114MB of K/V re-fetch at ~900cy latency).
//   - 32 Q-tiles of 64 rows; block handles pair (31-px, px) SEQUENTIALLY:
//     (31-px+1)+(px+1) = 33 chunk-phases for EVERY block. Grid (16,64) =
//     1024 identical blocks = exactly 4 blocks/CU, zero tail.
//   - Wave owns 16 Q rows (no mt dim): all 4 waves compute every chunk,
//     no divergent skip; LDS = K/V dbuf 32KB + p_lds 8KB = 40KB ->
//     4 blocks/CU resident = 16 waves/CU steady (was avg 4.8).
//   - XCD-clustered remap (proven in round 1: FETCH 146->24MB): all 16
//     blocks of a bh on one XCD; 8 bh/XCD = 4MB K/V = L2-resident, so
//     staging loads are ~200cy L2 hits, barrier drain cheap.
//   - Staging stream is continuous across the tile pair: during the last
//     chunk of tile A, stage chunk 0 of tile B (buffer parity continues).
// S^T = K Q^T (A=K-frag, B=Q-frag) so each lane owns ONE query row (l16):
//   - P packed via v_perm -> ds_write_b64 (4 writes/chunk, XOR-swizzled)
//   - row-sum l is a per-lane scalar (2 shfls per tile at the end)
// PV computes O^T (A=V^T-frag, B=P from LDS). No-max softmax via exp2
// (Q pre-scaled by HD^-0.5 * log2 e). Output bf16 row-major (head concat).
__global__ __launch_bounds__(256, 4) void fattn_kernel(
    const short* __restrict__ Q,
    const short* __restrict__ K,
    const short* __restrict__ VT,
    short* __restrict__ O)
{
    __shared__ short Kl[2][64 * 64];
    __shared__ short Vl[2][64 * 64];
    __shared__ short p_lds[4][16 * 64];
    const int tid  = threadIdx.x;
    const int lane = tid & 63, wave = tid >> 6;
    const int quad = lane >> 4, l16 = lane & 15;

    // XCD-clustered remap (bijective): lin%8 = XCD under round-robin
    // dispatch; all 16 tile-pair blocks of one bh share one XCD.
    const int lin  = blockIdx.y * 16 + blockIdx.x;   // 0..1023
    const int xcd  = lin & 7;
    const int slot = lin >> 3;                       // 0..127
    const int bh   = xcd * 8 + (slot >> 4);          // 0..63
    const int px   = slot & 15;                      // 0..15
    const int tiles[2] = { 31 - px, px };            // heavy tile first

    const int bb = bh >> 4, hh = bh & 15;
    const size_t bhoff = (size_t)bh * (Tsz * HDs);
    const short* Qb = Q + bhoff;
    const short* Kb = K + bhoff;
    const short* Vb = VT + bhoff;

    // staging: 512 slots of 16B per 64x64 tile, 2 rounds of 256 threads.
    // slot s: row = s>>3, granule = s&7; fetch source granule (s&7)^(row&7)
    const int s_a = tid, s_b = tid + 256;
    const int ra = s_a >> 3, ga = (s_a & 7) ^ (ra & 7);
    const int rb = s_b >> 3, gb = (s_b & 7) ^ (rb & 7);

    short* pw = &p_lds[wave][0];
    // swizzled read offsets (shorts): granule g stored at g^(l16&7)
    const int rd0 = l16 * 64 + (((quad    ) ^ (l16 & 7)) << 3);
    const int rd1 = l16 * 64 + (((quad + 4) ^ (l16 & 7)) << 3);

    // Q B-fragments for both tiles upfront: lane n = query row l16, k = d
    bf16x8 bq[2][2];
#pragma unroll
    for (int ti = 0; ti < 2; ++ti) {
        const short* qp = Qb + (size_t)(tiles[ti] * 64 + wave * 16 + l16) * 64 + quad * 8;
        bq[ti][0] = *(const bf16x8*)qp;
        bq[ti][1] = *(const bf16x8*)(qp + 32);
    }

    auto stage = [&](int c64, int buf) {
        short* kb_l = &Kl[buf][0];
        short* vb_l = &Vl[buf][0];
        async_copy16(Kb + (((size_t)(c64 + ra)) << 6) + (ga << 3), kb_l + s_a * 8);
        async_copy16(Kb + (((size_t)(c64 + rb)) << 6) + (gb << 3), kb_l + s_b * 8);
        async_copy16(Vb + ((size_t)ra << 11) + c64 + (ga << 3), vb_l + s_a * 8);
        async_copy16(Vb + ((size_t)rb << 11) + c64 + (gb << 3), vb_l + s_b * 8);
    };

    stage(tiles[0] * 0, 0);     // tile A chunk 0
    __syncthreads();            // compiler drains vmcnt before s_barrier

    int phase = 0;
#pragma unroll
    for (int ti = 0; ti < 2; ++ti) {
        const int tile = tiles[ti];
        const int q0w  = tile * 64 + wave * 16;   // wave's first query row
        const int nch  = tile + 1;

        f32x4 oaccT[4];
        float lacc = 0.f;
#pragma unroll
        for (int nt = 0; nt < 4; ++nt) oaccT[nt] = f32x4{0.f, 0.f, 0.f, 0.f};

        for (int c = 0; c < nch; ++c) {
            const int cur = phase & 1;
            if (c + 1 < nch)   stage((c + 1) * 64, cur ^ 1);
            else if (ti == 0)  stage(0, cur ^ 1);    // tile B chunk 0

            const int s0 = c * 64;
            const short* Kc = &Kl[cur][0];
            const short* Vc = &Vl[cur][0];
            // ---- K / V^T A-fragments from LDS (swizzled, balanced b128) ----
            bf16x8 ak[4][2], av[4][2];
#pragma unroll
            for (int ct = 0; ct < 4; ++ct) {
                const int r = ct * 16 + l16;
                ak[ct][0] = *(const bf16x8*)(Kc + r * 64 + (((quad    ) ^ (r & 7)) << 3));
                ak[ct][1] = *(const bf16x8*)(Kc + r * 64 + (((quad + 4) ^ (r & 7)) << 3));
            }
#pragma unroll
            for (int nt = 0; nt < 4; ++nt) {
                const int r = nt * 16 + l16;
                av[nt][0] = *(const bf16x8*)(Vc + r * 64 + (((quad    ) ^ (r & 7)) << 3));
                av[nt][1] = *(const bf16x8*)(Vc + r * 64 + (((quad + 4) ^ (r & 7)) << 3));
            }
            // ---- S^T = K Q^T : D col = query row (l16), row = key pos ----
            f32x4 sfr[4];
#pragma unroll
            for (int ct = 0; ct < 4; ++ct) {
                f32x4 cc = {0.f, 0.f, 0.f, 0.f};
                cc = __builtin_amdgcn_mfma_f32_16x16x32_bf16(ak[ct][0], bq[ti][0], cc, 0, 0, 0);
                cc = __builtin_amdgcn_mfma_f32_16x16x32_bf16(ak[ct][1], bq[ti][1], cc, 0, 0, 0);
                sfr[ct] = cc;
            }
            // ---- causal mask (only the diagonal chunk) ----
            if (s0 + 63 > q0w) {
                const int qr = q0w + l16;
#pragma unroll
                for (int ct = 0; ct < 4; ++ct)
#pragma unroll
                    for (int r = 0; r < 4; ++r)
                        if (s0 + ct * 16 + quad * 4 + r > qr)
                            sfr[ct][r] = -INFINITY;
            }
            // ---- P = exp2(S); scalar row-sum; packed b64 LDS writes ----
#pragma unroll
            for (int ct = 0; ct < 4; ++ct) {
                float p0 = __builtin_exp2f(sfr[ct][0]);
                float p1 = __builtin_exp2f(sfr[ct][1]);
                float p2 = __builtin_exp2f(sfr[ct][2]);
                float p3 = __builtin_exp2f(sfr[ct][3]);
                lacc += (p0 + p1) + (p2 + p3);
                uint2 pkv;
                pkv.x = pack_bf16(p1, p0);
                pkv.y = pack_bf16(p3, p2);
                const int g = (2 * ct + (quad >> 1)) ^ (l16 & 7);
                *(uint2*)(pw + l16 * 64 + (g << 3) + (quad & 1) * 4) = pkv;
            }
            // ---- P back as B-fragments (balanced b128 reads) ----
            bf16x8 bp0 = *(const bf16x8*)(pw + rd0);
            bf16x8 bp1 = *(const bf16x8*)(pw + rd1);
            // ---- O^T += V^T P^T : D col = query row, row = head dim ----
#pragma unroll
            for (int nt = 0; nt < 4; ++nt) {
                oaccT[nt] = __builtin_amdgcn_mfma_f32_16x16x32_bf16(av[nt][0], bp0, oaccT[nt], 0, 0, 0);
                oaccT[nt] = __builtin_amdgcn_mfma_f32_16x16x32_bf16(av[nt][1], bp1, oaccT[nt], 0, 0, 0);
            }
            __syncthreads();   // next stage drained; all waves done with cur
            ++phase;
        }

        // ---- finalize tile: reduce l across quads, normalize, store ----
        float ps = lacc;
        ps += __shfl_xor(ps, 16);
        ps += __shfl_xor(ps, 32);
        const float inv = 1.f / ps;
        short* orow = O + (size_t)(bb * Tsz + q0w + l16) * Dsz + hh * 64;
#pragma unroll
        for (int nt = 0; nt < 4; ++nt) {
            uint2 pkv;
            pkv.x = pack_bf16(oaccT[nt][1] * inv, oaccT[nt][0] * inv);
            pkv.y = pack_bf16(oaccT[nt][3] * inv, oaccT[nt][2] * inv);
            *(uint2*)(orow + nt * 16 + quad * 4) = pkv;
        }
    }
}

extern "C" void kernel_launch(void* const* d_in, const int* in_sizes, int n_in,
                              void* d_out, int out_size, void* d_ws, size_t ws_size,
                              hipStream_t stream) {
    const float* x   = (const float*)d_in[0];
    const float* Wq  = (const float*)d_in[1];
    const float* Wk  = (const float*)d_in[2];
    const float* Wv  = (const float*)d_in[3];
    const float* Wp  = (const float*)d_in[4];
    const float* bp  = (const float*)d_in[5];
    const float* W1  = (const float*)d_in[6];
    const float* b1  = (const float*)d_in[7];
    const float* W2  = (const float*)d_in[8];
    const float* b2  = (const float*)d_in[9];
    const float* g1  = (const float*)d_in[10];
    const float* be1 = (const float*)d_in[11];
    const float* g2  = (const float*)d_in[12];
    const float* be2 = (const float*)d_in[13];
    float* out = (float*)d_out;
    char*  W   = (char*)d_ws;

    short* h1  = (short*)(W);
    short* ff1 = (short*)(W);
    short* qb  = (short*)(W + (16ull << 20));
    short* kb  = (short*)(W + (32ull << 20));
    short* vtb = (short*)(W + (48ull << 20));
    short* o   = (short*)(W + (64ull << 20));
    short* h2  = (short*)(W + (80ull << 20));
    short* wqt = (short*)(W + (96ull << 20));
    short* wpt = (short*)(W + (102ull << 20));
    short* w1t = (short*)(W + (104ull << 20));
    short* w2t = (short*)(W + (112ull << 20));

    const int M = Bsz * Tsz;  // 8192
    // Q scale folds softmax's HD^-0.5 and exp->exp2 conversion (log2 e).
    const float qscale = 0.125f * 1.44269504f;

    transpose_cvt_qkv<<<dim3(2, 32, 48), 256, 0, stream>>>(Wq, Wk, Wv, wqt);
    transpose_cvt<<<dim3(32, 32, 1),  256, 0, stream>>>(Wp, wpt, 1024, 1024);
    transpose_cvt<<<dim3(128, 32, 1), 256, 0, stream>>>(W1, w1t, 1024, 4096);
    transpose_cvt<<<dim3(32, 128, 1), 256, 0, stream>>>(W2, w2t, 4096, 1024);

    ln_kernel<<<dim3(M), 256, 0, stream>>>(x, g1, be1, h1);

    gemm_mfma<0><<<dim3(24, 64), 256, 0, stream>>>(
        h1, wqt, nullptr, nullptr, nullptr, qb, kb, vtb, M, 3072, 1024, qscale);

    fattn_kernel<<<dim3(16, Bsz * Hn), 256, 0, stream>>>(qb, kb, vtb, o);

    gemm_n64<<<dim3(16, 64), 256, 0, stream>>>(
        o, wpt, bp, x, out, M, 1024, 1024);

    ln_kernel<<<dim3(M), 256, 0, stream>>>(out, g2, be2, h2);

    gemm_mfma<3><<<dim3(32, 64), 256, 0, stream>>>(
        h2, w1t, b1, nullptr, nullptr, ff1, nullptr, nullptr, M, 4096, 1024, 1.f);

    gemm_n64<<<dim3(16, 64), 256, 0, stream>>>(
        ff1, w2t, b2, out, out, M, 1024, 4096);
}

// Round 6
// 537.905 us; speedup vs baseline: 1.0282x; 1.0282x over previous
//
#include <hip/hip_runtime.h>
#include <hip/hip_bf16.h>
#include <math.h>

#define Bsz 4
#define Tsz 2048
#define Dsz 1024
#define Hn  16
#define HDs 64

typedef __attribute__((ext_vector_type(8))) short bf16x8;
typedef __attribute__((ext_vector_type(4))) float f32x4;

typedef const __attribute__((address_space(1))) void gvoid;
typedef __attribute__((address_space(3))) void lvoid;

__device__ __forceinline__ void async_copy16(const short* g, short* l) {
    __builtin_amdgcn_global_load_lds((gvoid*)g, (lvoid*)l, 16, 0, 0);
}

__device__ __forceinline__ short f2bf(float x) {
    __hip_bfloat16 h = __float2bfloat16(x);
    return *reinterpret_cast<short*>(&h);
}

// pack two fp32 -> two bf16 in one u32 (round-half-up via +0x8000, then
// v_perm grabs the high shorts). lo -> low half, hi -> high half.
__device__ __forceinline__ unsigned int pack_bf16(float hi, float lo) {
    unsigned int uh = __float_as_uint(hi) + 0x8000u;
    unsigned int ul = __float_as_uint(lo) + 0x8000u;
    return __builtin_amdgcn_perm(uh, ul, 0x07060302u);
}

// index into [b, h, t, kc] tensor given m = b*T + t, c = h*64 + kc
__device__ __forceinline__ size_t headed_idx(int m, int c) {
    int b = m >> 11, t = m & 2047, h = c >> 6, kc = c & 63;
    return (((size_t)(b * Hn + h) * Tsz + t) << 6) + kc;
}

// ---------------- LayerNorm: fp32 in, bf16 out -----------------------------
__global__ __launch_bounds__(256) void ln_kernel(const float* __restrict__ x,
                                                 const float* __restrict__ g,
                                                 const float* __restrict__ beta,
                                                 short* __restrict__ out)
{
    const int row = blockIdx.x;
    const float* xr = x + (size_t)row * Dsz;
    float v[4];
    float s = 0.f, s2 = 0.f;
#pragma unroll
    for (int i = 0; i < 4; ++i) {
        v[i] = xr[threadIdx.x + 256 * i];
        s += v[i];
        s2 += v[i] * v[i];
    }
#pragma unroll
    for (int off = 32; off; off >>= 1) {
        s  += __shfl_xor(s,  off);
        s2 += __shfl_xor(s2, off);
    }
    __shared__ float red[8];
    const int wave = threadIdx.x >> 6;
    if ((threadIdx.x & 63) == 0) { red[wave * 2] = s; red[wave * 2 + 1] = s2; }
    __syncthreads();
    s  = red[0] + red[2] + red[4] + red[6];
    s2 = red[1] + red[3] + red[5] + red[7];
    const float mu  = s * (1.f / Dsz);
    const float var = s2 * (1.f / Dsz) - mu * mu;
    const float rs  = rsqrtf(var + 1e-5f);
    short* orow = out + (size_t)row * Dsz;
#pragma unroll
    for (int i = 0; i < 4; ++i) {
        int col = threadIdx.x + 256 * i;
        orow[col] = f2bf((v[i] - mu) * rs * g[col] + beta[col]);
    }
}

// ---------------- fp32 [R][C] slice -> bf16 [C][R] (weight prep) -----------
__global__ __launch_bounds__(256) void transpose_cvt(
    const float* __restrict__ in, short* __restrict__ outp, int R, int C)
{
    __shared__ float tile[32][33];
    const int r0 = blockIdx.y * 32, c0 = blockIdx.x * 32;
    const size_t so = (size_t)blockIdx.z * R * C;
    const int tx = threadIdx.x & 31, ty = threadIdx.x >> 5;
    const float* ip = in + so;
    short* op = outp + so;
#pragma unroll
    for (int i = 0; i < 4; ++i)
        tile[ty + i * 8][tx] = ip[(size_t)(r0 + ty + i * 8) * C + c0 + tx];
    __syncthreads();
#pragma unroll
    for (int i = 0; i < 4; ++i)
        op[(size_t)(c0 + ty + i * 8) * R + r0 + tx] = f2bf(tile[tx][ty + i * 8]);
}

// QKV variant: z 0..47 selects Wq/Wk/Wv head slices, outputs contiguous.
__global__ __launch_bounds__(256) void transpose_cvt_qkv(
    const float* __restrict__ Wq, const float* __restrict__ Wk,
    const float* __restrict__ Wv, short* __restrict__ outp)
{
    __shared__ float tile[32][33];
    const int z = blockIdx.z;
    const float* in = (z < 16) ? Wq : (z < 32) ? Wk : Wv;
    const int zz = z & 15;
    const int r0 = blockIdx.y * 32, c0 = blockIdx.x * 32;
    const int tx = threadIdx.x & 31, ty = threadIdx.x >> 5;
    const float* ip = in + (size_t)zz * (1024 * 64);
    short* op = outp + (size_t)z * (1024 * 64);
#pragma unroll
    for (int i = 0; i < 4; ++i)
        tile[ty + i * 8][tx] = ip[(size_t)(r0 + ty + i * 8) * 64 + c0 + tx];
    __syncthreads();
#pragma unroll
    for (int i = 0; i < 4; ++i)
        op[(size_t)(c0 + ty + i * 8) * 1024 + r0 + tx] = f2bf(tile[tx][ty + i * 8]);
}

// ---------------- bf16 MFMA GEMM, double-buffered m97 structure ------------
// C[M][N] = A[M][K] (row-major bf16) * Bt[N][K]^T (bf16).
// 128x128 tile, BK=32, 4 waves each computing 64x64 (4x4 of 16x16x32 MFMA).
// v5: XCD-grouped block remap: each XCD owns 8 consecutive m-rows x all
// n-cols (REQUIRES gridDim.y == 64). FETCH 288->82MB.
// v7: double-buffered staging (round-5 post-mortem: the single-buffer loop
// stage -> barrier(vmcnt0 drains JUST-issued loads) -> compute exposed the
// full global latency every K-step on every block). Now: stage(t+1) into
// buf^1 BEFORE computing buf t; ONE barrier per step - its vmcnt(0) drain
// waits on loads issued a full compute-phase earlier (T3 minimum recipe).
// EPI 0: fused QKV epilogue (N=3072): n<1024 -> Q headed *scale,
//        <2048 -> K headed, else V^T [b,h,kc,t]
// EPI 2: fp32 row-major, + bias + resid
// EPI 3: bf16 row-major, relu(+bias)
template <int EPI>
__global__ __launch_bounds__(256) void gemm_mfma(
    const short* __restrict__ A, const short* __restrict__ Bt,
    const float* __restrict__ bias, const float* __restrict__ resid,
    float* __restrict__ Cf, short* __restrict__ Cb0,
    short* __restrict__ Cb1, short* __restrict__ Cb2,
    int M, int N, int K, float scale)
{
    __shared__ short As[2][128 * 32];
    __shared__ short Bs[2][128 * 32];
    const int tid  = threadIdx.x;
    const int lane = tid & 63, wave = tid >> 6;
    const int quad = lane >> 4, l16 = lane & 15;

    // XCD-grouped remap: lin%8 = XCD under round-robin dispatch.
    // XCD owns m-rows [xcd*8, xcd*8+8) x all n. (gridDim.y == 64.)
    const int lin = blockIdx.y * gridDim.x + blockIdx.x;
    const int xcd = lin & 7;
    const int s   = lin >> 3;
    const int my  = xcd * 8 + (s & 7);   // m-row within 64
    const int nx  = s >> 3;              // n-col 0..gridDim.x-1
    const int m0 = my * 128, n0 = nx * 128;

    const int wm = (wave >> 1) * 64, wn = (wave & 1) * 64;

    f32x4 acc[4][4];
#pragma unroll
    for (int i = 0; i < 4; ++i)
#pragma unroll
        for (int j = 0; j < 4; ++j) acc[i][j] = f32x4{0.f, 0.f, 0.f, 0.f};

    const short* gA = A  + (size_t)(m0 + wave * 32 + (lane >> 2)) * K + (lane & 3) * 8;
    const short* gB = Bt + (size_t)(n0 + wave * 32 + (lane >> 2)) * K + (lane & 3) * 8;
    const size_t rstep = (size_t)16 * K;
    const int woff = wave * 1024;

    // prologue: stage k=0 into buffer 0
    async_copy16(gA,         &As[0][woff]);
    async_copy16(gA + rstep, &As[0][woff + 512]);
    async_copy16(gB,         &Bs[0][woff]);
    async_copy16(gB + rstep, &Bs[0][woff + 512]);
    gA += 32; gB += 32;
    __syncthreads();

    int cur = 0;
    for (int k0 = 0; k0 < K; k0 += 32) {
        if (k0 + 32 < K) {
            const int nxt = cur ^ 1;
            async_copy16(gA,         &As[nxt][woff]);
            async_copy16(gA + rstep, &As[nxt][woff + 512]);
            async_copy16(gB,         &Bs[nxt][woff]);
            async_copy16(gB + rstep, &Bs[nxt][woff + 512]);
            gA += 32; gB += 32;
        }
        bf16x8 af[4], bfr[4];
#pragma unroll
        for (int mt = 0; mt < 4; ++mt)
            af[mt] = *(const bf16x8*)(&As[cur][(wm + mt * 16 + l16) * 32 + quad * 8]);
#pragma unroll
        for (int nt = 0; nt < 4; ++nt)
            bfr[nt] = *(const bf16x8*)(&Bs[cur][(wn + nt * 16 + l16) * 32 + quad * 8]);
#pragma unroll
        for (int mt = 0; mt < 4; ++mt)
#pragma unroll
            for (int nt = 0; nt < 4; ++nt)
                acc[mt][nt] = __builtin_amdgcn_mfma_f32_16x16x32_bf16(
                    af[mt], bfr[nt], acc[mt][nt], 0, 0, 0);
        __syncthreads();   // drains next-tile loads; all waves done with cur
        cur ^= 1;
    }

#pragma unroll
    for (int mt = 0; mt < 4; ++mt) {
#pragma unroll
        for (int nt = 0; nt < 4; ++nt) {
#pragma unroll
            for (int r = 0; r < 4; ++r) {
                const int m = m0 + wm + mt * 16 + quad * 4 + r;
                const int c = n0 + wn + nt * 16 + l16;
                float val = acc[mt][nt][r];
                if (EPI == 0) {
                    const int sel = c >> 10, cl = c & 1023;
                    if (sel == 0)
                        Cb0[headed_idx(m, cl)] = f2bf(val * scale);
                    else if (sel == 1)
                        Cb1[headed_idx(m, cl)] = f2bf(val);
                    else {
                        int b = m >> 11, t = m & 2047;
                        size_t idx = ((((size_t)((b << 4) | (cl >> 6)) << 6) | (cl & 63)) << 11) | t;
                        Cb2[idx] = f2bf(val);
                    }
                } else if (EPI == 2) {
                    size_t idx = (size_t)m * N + c;
                    Cf[idx] = val + bias[c] + resid[idx];
                } else {  // EPI 3
                    float v2 = val + bias[c];
                    Cb0[(size_t)m * N + c] = f2bf(v2 > 0.f ? v2 : 0.f);
                }
            }
        }
    }
}

// ---------------- narrow-N bf16 MFMA GEMM (128x64 tile, BK=64) -------------
// v6: for the two N=1024 GEMMs (proj, FFN2): grid (16,64) = 1024 blocks.
// LDS [row][64] rows XOR-swizzled (g^(row&7)) via pre-swizzled global
// source + linear LDS dest -> 0 bank conflicts (round-5 PMC).
// v7: double-buffered (round-5 post-mortem: 555 TF, 15% HBM, traffic ==
// compulsory, conflicts == 0 -> the only remaining cost was the exposed
// per-step global latency of the stage->drain->compute loop). Stage(t+1)
// before compute(t); one barrier per step. LDS 48KB -> 3 blocks/CU.
// Epilogue = fp32 row-major, + bias + resid. REQUIRES grid (16,64).
__global__ __launch_bounds__(256) void gemm_n64(
    const short* __restrict__ A, const short* __restrict__ Bt,
    const float* __restrict__ bias, const float* __restrict__ resid,
    float* __restrict__ Cf, int M, int N, int K)
{
    __shared__ short As[2][128 * 64];   // 2 x 16 KB
    __shared__ short Bs[2][64 * 64];    // 2 x 8 KB
    const int tid  = threadIdx.x;
    const int lane = tid & 63, wave = tid >> 6;
    const int quad = lane >> 4, l16 = lane & 15;

    const int lin = blockIdx.y * 16 + blockIdx.x;   // grid (16,64)
    const int xcd = lin & 7;
    const int s   = lin >> 3;                       // 0..127
    const int m0  = (xcd * 8 + (s & 7)) * 128;
    const int n0  = (s >> 3) * 64;

    const int wm = (wave >> 1) * 64, wn = (wave & 1) * 32;

    f32x4 acc[4][2];
#pragma unroll
    for (int i = 0; i < 4; ++i)
#pragma unroll
        for (int j = 0; j < 2; ++j) acc[i][j] = f32x4{0.f, 0.f, 0.f, 0.f};

    // staging: A 128x64 shorts = 1024 granules (4/thread), B 64x64 = 512
    // (2/thread). slot sl: row = sl>>3, LDS pos = sl&7, source granule
    // (sl&7)^(row&7) so reads can XOR the same way.
    const short* gA[4];
    const short* gB[2];
    int dA[4], dB[2];
#pragma unroll
    for (int i = 0; i < 4; ++i) {
        const int sl = tid + 256 * i, r = sl >> 3, g = (sl & 7) ^ (r & 7);
        gA[i] = A + (size_t)(m0 + r) * K + g * 8;
        dA[i] = sl * 8;
    }
#pragma unroll
    for (int i = 0; i < 2; ++i) {
        const int sl = tid + 256 * i, r = sl >> 3, g = (sl & 7) ^ (r & 7);
        gB[i] = Bt + (size_t)(n0 + r) * K + g * 8;
        dB[i] = sl * 8;
    }

    // prologue: stage k=0 into buffer 0
#pragma unroll
    for (int i = 0; i < 4; ++i) { async_copy16(gA[i], &As[0][dA[i]]); gA[i] += 64; }
#pragma unroll
    for (int i = 0; i < 2; ++i) { async_copy16(gB[i], &Bs[0][dB[i]]); gB[i] += 64; }
    __syncthreads();

    int cur = 0;
    for (int k0 = 0; k0 < K; k0 += 64) {
        if (k0 + 64 < K) {
            const int nxt = cur ^ 1;
#pragma unroll
            for (int i = 0; i < 4; ++i) { async_copy16(gA[i], &As[nxt][dA[i]]); gA[i] += 64; }
#pragma unroll
            for (int i = 0; i < 2; ++i) { async_copy16(gB[i], &Bs[nxt][dB[i]]); gB[i] += 64; }
        }
        bf16x8 af[4][2], bfr[2][2];
#pragma unroll
        for (int mt = 0; mt < 4; ++mt) {
            const int r = wm + mt * 16 + l16;
            af[mt][0] = *(const bf16x8*)(&As[cur][r * 64 + (((quad    ) ^ (r & 7)) << 3)]);
            af[mt][1] = *(const bf16x8*)(&As[cur][r * 64 + (((quad + 4) ^ (r & 7)) << 3)]);
        }
#pragma unroll
        for (int nt = 0; nt < 2; ++nt) {
            const int r = wn + nt * 16 + l16;
            bfr[nt][0] = *(const bf16x8*)(&Bs[cur][r * 64 + (((quad    ) ^ (r & 7)) << 3)]);
            bfr[nt][1] = *(const bf16x8*)(&Bs[cur][r * 64 + (((quad + 4) ^ (r & 7)) << 3)]);
        }
#pragma unroll
        for (int mt = 0; mt < 4; ++mt)
#pragma unroll
            for (int nt = 0; nt < 2; ++nt) {
                acc[mt][nt] = __builtin_amdgcn_mfma_f32_16x16x32_bf16(
                    af[mt][0], bfr[nt][0], acc[mt][nt], 0, 0, 0);
                acc[mt][nt] = __builtin_amdgcn_mfma_f32_16x16x32_bf16(
                    af[mt][1], bfr[nt][1], acc[mt][nt], 0, 0, 0);
            }
        __syncthreads();   // drains next-tile loads; all waves done with cur
        cur ^= 1;
    }

#pragma unroll
    for (int mt = 0; mt < 4; ++mt) {
#pragma unroll
        for (int nt = 0; nt < 2; ++nt) {
#pragma unroll
            for (int r = 0; r < 4; ++r) {
                const int m = m0 + wm + mt * 16 + quad * 4 + r;
                const int c = n0 + wn + nt * 16 + l16;
                const size_t idx = (size_t)m * N + c;
                Cf[idx] = acc[mt][nt][r] + bias[c] + resid[idx];
            }
        }
    }
}

// ---------------- MFMA flash attention, LDS-staged K/V ---------------------
// v4: balance + occupancy + L2 residency (round-2 post-mortem: avg 4.8
// waves/CU, 91% stall; FETCH 114MB of K/V re-fetch at ~900cy latency).
//   - 32 Q-tiles of 64 rows; block handles pair (31-px, px) SEQUENTIALLY:
//     (31-px+1)+(px+1) = 33 chunk-phases for EVERY block. Grid (16,64) =
//     1024 identical blocks = exactly 4 blocks/CU, zero tail.
//   - Wave owns 16 Q rows (no mt dim): all 4 waves compute every chunk,
//     no divergent skip; LDS = K/V dbuf 32KB + p_lds 8KB = 40KB ->
//     4 blocks/CU resident = 16 waves/CU steady (was avg 4.8).
//   - XCD-clustered remap (proven in round 1: FETCH 146->24MB): all 16
//     blocks of a bh on one XCD; 8 bh/XCD = 4MB K/V = L2-resident, so
//     staging loads are ~200cy L2 hits, barrier drain cheap.
//   - Staging stream is continuous across the tile pair: during the last
//     chunk of tile A, stage chunk 0 of tile B (buffer parity continues).
// S^T = K Q^T (A=K-frag, B=Q-frag) so each lane owns ONE query row (l16):
//   - P packed via v_perm -> ds_write_b64 (4 writes/chunk, XOR-swizzled)
//   - row-sum l is a per-lane scalar (2 shfls per tile at the end)
// PV computes O^T (A=V^T-frag, B=P from LDS). No-max softmax via exp2
// (Q pre-scaled by HD^-0.5 * log2 e). Output bf16 row-major (head concat).
__global__ __launch_bounds__(256, 4) void fattn_kernel(
    const short* __restrict__ Q,
    const short* __restrict__ K,
    const short* __restrict__ VT,
    short* __restrict__ O)
{
    __shared__ short Kl[2][64 * 64];
    __shared__ short Vl[2][64 * 64];
    __shared__ short p_lds[4][16 * 64];
    const int tid  = threadIdx.x;
    const int lane = tid & 63, wave = tid >> 6;
    const int quad = lane >> 4, l16 = lane & 15;

    // XCD-clustered remap (bijective): lin%8 = XCD under round-robin
    // dispatch; all 16 tile-pair blocks of one bh share one XCD.
    const int lin  = blockIdx.y * 16 + blockIdx.x;   // 0..1023
    const int xcd  = lin & 7;
    const int slot = lin >> 3;                       // 0..127
    const int bh   = xcd * 8 + (slot >> 4);          // 0..63
    const int px   = slot & 15;                      // 0..15
    const int tiles[2] = { 31 - px, px };            // heavy tile first

    const int bb = bh >> 4, hh = bh & 15;
    const size_t bhoff = (size_t)bh * (Tsz * HDs);
    const short* Qb = Q + bhoff;
    const short* Kb = K + bhoff;
    const short* Vb = VT + bhoff;

    // staging: 512 slots of 16B per 64x64 tile, 2 rounds of 256 threads.
    // slot s: row = s>>3, granule = s&7; fetch source granule (s&7)^(row&7)
    const int s_a = tid, s_b = tid + 256;
    const int ra = s_a >> 3, ga = (s_a & 7) ^ (ra & 7);
    const int rb = s_b >> 3, gb = (s_b & 7) ^ (rb & 7);

    short* pw = &p_lds[wave][0];
    // swizzled read offsets (shorts): granule g stored at g^(l16&7)
    const int rd0 = l16 * 64 + (((quad    ) ^ (l16 & 7)) << 3);
    const int rd1 = l16 * 64 + (((quad + 4) ^ (l16 & 7)) << 3);

    // Q B-fragments for both tiles upfront: lane n = query row l16, k = d
    bf16x8 bq[2][2];
#pragma unroll
    for (int ti = 0; ti < 2; ++ti) {
        const short* qp = Qb + (size_t)(tiles[ti] * 64 + wave * 16 + l16) * 64 + quad * 8;
        bq[ti][0] = *(const bf16x8*)qp;
        bq[ti][1] = *(const bf16x8*)(qp + 32);
    }

    auto stage = [&](int c64, int buf) {
        short* kb_l = &Kl[buf][0];
        short* vb_l = &Vl[buf][0];
        async_copy16(Kb + (((size_t)(c64 + ra)) << 6) + (ga << 3), kb_l + s_a * 8);
        async_copy16(Kb + (((size_t)(c64 + rb)) << 6) + (gb << 3), kb_l + s_b * 8);
        async_copy16(Vb + ((size_t)ra << 11) + c64 + (ga << 3), vb_l + s_a * 8);
        async_copy16(Vb + ((size_t)rb << 11) + c64 + (gb << 3), vb_l + s_b * 8);
    };

    stage(tiles[0] * 0, 0);     // tile A chunk 0
    __syncthreads();            // compiler drains vmcnt before s_barrier

    int phase = 0;
#pragma unroll
    for (int ti = 0; ti < 2; ++ti) {
        const int tile = tiles[ti];
        const int q0w  = tile * 64 + wave * 16;   // wave's first query row
        const int nch  = tile + 1;

        f32x4 oaccT[4];
        float lacc = 0.f;
#pragma unroll
        for (int nt = 0; nt < 4; ++nt) oaccT[nt] = f32x4{0.f, 0.f, 0.f, 0.f};

        for (int c = 0; c < nch; ++c) {
            const int cur = phase & 1;
            if (c + 1 < nch)   stage((c + 1) * 64, cur ^ 1);
            else if (ti == 0)  stage(0, cur ^ 1);    // tile B chunk 0

            const int s0 = c * 64;
            const short* Kc = &Kl[cur][0];
            const short* Vc = &Vl[cur][0];
            // ---- K / V^T A-fragments from LDS (swizzled, balanced b128) ----
            bf16x8 ak[4][2], av[4][2];
#pragma unroll
            for (int ct = 0; ct < 4; ++ct) {
                const int r = ct * 16 + l16;
                ak[ct][0] = *(const bf16x8*)(Kc + r * 64 + (((quad    ) ^ (r & 7)) << 3));
                ak[ct][1] = *(const bf16x8*)(Kc + r * 64 + (((quad + 4) ^ (r & 7)) << 3));
            }
#pragma unroll
            for (int nt = 0; nt < 4; ++nt) {
                const int r = nt * 16 + l16;
                av[nt][0] = *(const bf16x8*)(Vc + r * 64 + (((quad    ) ^ (r & 7)) << 3));
                av[nt][1] = *(const bf16x8*)(Vc + r * 64 + (((quad + 4) ^ (r & 7)) << 3));
            }
            // ---- S^T = K Q^T : D col = query row (l16), row = key pos ----
            f32x4 sfr[4];
#pragma unroll
            for (int ct = 0; ct < 4; ++ct) {
                f32x4 cc = {0.f, 0.f, 0.f, 0.f};
                cc = __builtin_amdgcn_mfma_f32_16x16x32_bf16(ak[ct][0], bq[ti][0], cc, 0, 0, 0);
                cc = __builtin_amdgcn_mfma_f32_16x16x32_bf16(ak[ct][1], bq[ti][1], cc, 0, 0, 0);
                sfr[ct] = cc;
            }
            // ---- causal mask (only the diagonal chunk) ----
            if (s0 + 63 > q0w) {
                const int qr = q0w + l16;
#pragma unroll
                for (int ct = 0; ct < 4; ++ct)
#pragma unroll
                    for (int r = 0; r < 4; ++r)
                        if (s0 + ct * 16 + quad * 4 + r > qr)
                            sfr[ct][r] = -INFINITY;
            }
            // ---- P = exp2(S); scalar row-sum; packed b64 LDS writes ----
#pragma unroll
            for (int ct = 0; ct < 4; ++ct) {
                float p0 = __builtin_exp2f(sfr[ct][0]);
                float p1 = __builtin_exp2f(sfr[ct][1]);
                float p2 = __builtin_exp2f(sfr[ct][2]);
                float p3 = __builtin_exp2f(sfr[ct][3]);
                lacc += (p0 + p1) + (p2 + p3);
                uint2 pkv;
                pkv.x = pack_bf16(p1, p0);
                pkv.y = pack_bf16(p3, p2);
                const int g = (2 * ct + (quad >> 1)) ^ (l16 & 7);
                *(uint2*)(pw + l16 * 64 + (g << 3) + (quad & 1) * 4) = pkv;
            }
            // ---- P back as B-fragments (balanced b128 reads) ----
            bf16x8 bp0 = *(const bf16x8*)(pw + rd0);
            bf16x8 bp1 = *(const bf16x8*)(pw + rd1);
            // ---- O^T += V^T P^T : D col = query row, row = head dim ----
#pragma unroll
            for (int nt = 0; nt < 4; ++nt) {
                oaccT[nt] = __builtin_amdgcn_mfma_f32_16x16x32_bf16(av[nt][0], bp0, oaccT[nt], 0, 0, 0);
                oaccT[nt] = __builtin_amdgcn_mfma_f32_16x16x32_bf16(av[nt][1], bp1, oaccT[nt], 0, 0, 0);
            }
            __syncthreads();   // next stage drained; all waves done with cur
            ++phase;
        }

        // ---- finalize tile: reduce l across quads, normalize, store ----
        float ps = lacc;
        ps += __shfl_xor(ps, 16);
        ps += __shfl_xor(ps, 32);
        const float inv = 1.f / ps;
        short* orow = O + (size_t)(bb * Tsz + q0w + l16) * Dsz + hh * 64;
#pragma unroll
        for (int nt = 0; nt < 4; ++nt) {
            uint2 pkv;
            pkv.x = pack_bf16(oaccT[nt][1] * inv, oaccT[nt][0] * inv);
            pkv.y = pack_bf16(oaccT[nt][3] * inv, oaccT[nt][2] * inv);
            *(uint2*)(orow + nt * 16 + quad * 4) = pkv;
        }
    }
}

extern "C" void kernel_launch(void* const* d_in, const int* in_sizes, int n_in,
                              void* d_out, int out_size, void* d_ws, size_t ws_size,
                              hipStream_t stream) {
    const float* x   = (const float*)d_in[0];
    const float* Wq  = (const float*)d_in[1];
    const float* Wk  = (const float*)d_in[2];
    const float* Wv  = (const float*)d_in[3];
    const float* Wp  = (const float*)d_in[4];
    const float* bp  = (const float*)d_in[5];
    const float* W1  = (const float*)d_in[6];
    const float* b1  = (const float*)d_in[7];
    const float* W2  = (const float*)d_in[8];
    const float* b2  = (const float*)d_in[9];
    const float* g1  = (const float*)d_in[10];
    const float* be1 = (const float*)d_in[11];
    const float* g2  = (const float*)d_in[12];
    const float* be2 = (const float*)d_in[13];
    float* out = (float*)d_out;
    char*  W   = (char*)d_ws;

    short* h1  = (short*)(W);
    short* ff1 = (short*)(W);
    short* qb  = (short*)(W + (16ull << 20));
    short* kb  = (short*)(W + (32ull << 20));
    short* vtb = (short*)(W + (48ull << 20));
    short* o   = (short*)(W + (64ull << 20));
    short* h2  = (short*)(W + (80ull << 20));
    short* wqt = (short*)(W + (96ull << 20));
    short* wpt = (short*)(W + (102ull << 20));
    short* w1t = (short*)(W + (104ull << 20));
    short* w2t = (short*)(W + (112ull << 20));

    const int M = Bsz * Tsz;  // 8192
    // Q scale folds softmax's HD^-0.5 and exp->exp2 conversion (log2 e).
    const float qscale = 0.125f * 1.44269504f;

    transpose_cvt_qkv<<<dim3(2, 32, 48), 256, 0, stream>>>(Wq, Wk, Wv, wqt);
    transpose_cvt<<<dim3(32, 32, 1),  256, 0, stream>>>(Wp, wpt, 1024, 1024);
    transpose_cvt<<<dim3(128, 32, 1), 256, 0, stream>>>(W1, w1t, 1024, 4096);
    transpose_cvt<<<dim3(32, 128, 1), 256, 0, stream>>>(W2, w2t, 4096, 1024);

    ln_kernel<<<dim3(M), 256, 0, stream>>>(x, g1, be1, h1);

    gemm_mfma<0><<<dim3(24, 64), 256, 0, stream>>>(
        h1, wqt, nullptr, nullptr, nullptr, qb, kb, vtb, M, 3072, 1024, qscale);

    fattn_kernel<<<dim3(16, Bsz * Hn), 256, 0, stream>>>(qb, kb, vtb, o);

    gemm_n64<<<dim3(16, 64), 256, 0, stream>>>(
        o, wpt, bp, x, out, M, 1024, 1024);

    ln_kernel<<<dim3(M), 256, 0, stream>>>(out, g2, be2, h2);

    gemm_mfma<3><<<dim3(32, 64), 256, 0, stream>>>(
        h2, w1t, b1, nullptr, nullptr, ff1, nullptr, nullptr, M, 4096, 1024, 1.f);

    gemm_n64<<<dim3(16, 64), 256, 0, stream>>>(
        ff1, w2t, b2, out, out, M, 1024, 4096);
}

// Round 8
// 513.569 us; speedup vs baseline: 1.0769x; 1.0474x over previous
//
#include <hip/hip_runtime.h>
#include <hip/hip_bf16.h>
#include <math.h>

#define Bsz 4
#define Tsz 2048
#define Dsz 1024
#define Hn  16
#define HDs 64

typedef __attribute__((ext_vector_type(8))) short bf16x8;
typedef __attribute__((ext_vector_type(4))) float f32x4;

typedef const __attribute__((address_space(1))) void gvoid;
typedef __attribute__((address_space(3))) void lvoid;

__device__ __forceinline__ void async_copy16(const short* g, short* l) {
    __builtin_amdgcn_global_load_lds((gvoid*)g, (lvoid*)l, 16, 0, 0);
}

__device__ __forceinline__ short f2bf(float x) {
    __hip_bfloat16 h = __float2bfloat16(x);
    return *reinterpret_cast<short*>(&h);
}

// pack two fp32 -> two bf16 in one u32 (round-half-up via +0x8000, then
// v_perm grabs the high shorts). lo -> low half, hi -> high half.
__device__ __forceinline__ unsigned int pack_bf16(float hi, float lo) {
    unsigned int uh = __float_as_uint(hi) + 0x8000u;
    unsigned int ul = __float_as_uint(lo) + 0x8000u;
    return __builtin_amdgcn_perm(uh, ul, 0x07060302u);
}

// index into [b, h, t, kc] tensor given m = b*T + t, c = h*64 + kc
__device__ __forceinline__ size_t headed_idx(int m, int c) {
    int b = m >> 11, t = m & 2047, h = c >> 6, kc = c & 63;
    return (((size_t)(b * Hn + h) * Tsz + t) << 6) + kc;
}

// ---------------- LayerNorm: fp32 in, bf16 out -----------------------------
__global__ __launch_bounds__(256) void ln_kernel(const float* __restrict__ x,
                                                 const float* __restrict__ g,
                                                 const float* __restrict__ beta,
                                                 short* __restrict__ out)
{
    const int row = blockIdx.x;
    const float* xr = x + (size_t)row * Dsz;
    float v[4];
    float s = 0.f, s2 = 0.f;
#pragma unroll
    for (int i = 0; i < 4; ++i) {
        v[i] = xr[threadIdx.x + 256 * i];
        s += v[i];
        s2 += v[i] * v[i];
    }
#pragma unroll
    for (int off = 32; off; off >>= 1) {
        s  += __shfl_xor(s,  off);
        s2 += __shfl_xor(s2, off);
    }
    __shared__ float red[8];
    const int wave = threadIdx.x >> 6;
    if ((threadIdx.x & 63) == 0) { red[wave * 2] = s; red[wave * 2 + 1] = s2; }
    __syncthreads();
    s  = red[0] + red[2] + red[4] + red[6];
    s2 = red[1] + red[3] + red[5] + red[7];
    const float mu  = s * (1.f / Dsz);
    const float var = s2 * (1.f / Dsz) - mu * mu;
    const float rs  = rsqrtf(var + 1e-5f);
    short* orow = out + (size_t)row * Dsz;
#pragma unroll
    for (int i = 0; i < 4; ++i) {
        int col = threadIdx.x + 256 * i;
        orow[col] = f2bf((v[i] - mu) * rs * g[col] + beta[col]);
    }
}

// ---------------- fp32 [R][C] slice -> bf16 [C][R] (weight prep) -----------
__global__ __launch_bounds__(256) void transpose_cvt(
    const float* __restrict__ in, short* __restrict__ outp, int R, int C)
{
    __shared__ float tile[32][33];
    const int r0 = blockIdx.y * 32, c0 = blockIdx.x * 32;
    const size_t so = (size_t)blockIdx.z * R * C;
    const int tx = threadIdx.x & 31, ty = threadIdx.x >> 5;
    const float* ip = in + so;
    short* op = outp + so;
#pragma unroll
    for (int i = 0; i < 4; ++i)
        tile[ty + i * 8][tx] = ip[(size_t)(r0 + ty + i * 8) * C + c0 + tx];
    __syncthreads();
#pragma unroll
    for (int i = 0; i < 4; ++i)
        op[(size_t)(c0 + ty + i * 8) * R + r0 + tx] = f2bf(tile[tx][ty + i * 8]);
}

// QKV variant: z 0..47 selects Wq/Wk/Wv head slices, outputs contiguous.
__global__ __launch_bounds__(256) void transpose_cvt_qkv(
    const float* __restrict__ Wq, const float* __restrict__ Wk,
    const float* __restrict__ Wv, short* __restrict__ outp)
{
    __shared__ float tile[32][33];
    const int z = blockIdx.z;
    const float* in = (z < 16) ? Wq : (z < 32) ? Wk : Wv;
    const int zz = z & 15;
    const int r0 = blockIdx.y * 32, c0 = blockIdx.x * 32;
    const int tx = threadIdx.x & 31, ty = threadIdx.x >> 5;
    const float* ip = in + (size_t)zz * (1024 * 64);
    short* op = outp + (size_t)z * (1024 * 64);
#pragma unroll
    for (int i = 0; i < 4; ++i)
        tile[ty + i * 8][tx] = ip[(size_t)(r0 + ty + i * 8) * 64 + c0 + tx];
    __syncthreads();
#pragma unroll
    for (int i = 0; i < 4; ++i)
        op[(size_t)(c0 + ty + i * 8) * 1024 + r0 + tx] = f2bf(tile[tx][ty + i * 8]);
}

// ---------------- bf16 MFMA GEMM, counted-vmcnt pipeline -------------------
// C[M][N] = A[M][K] (row-major bf16) * Bt[N][K]^T (bf16).
// 128x128 tile, BK=32, 4 waves each computing 64x64 (4x4 of 16x16x32 MFMA).
// v5: XCD-grouped block remap: each XCD owns 8 consecutive m-rows x all
// n-cols (REQUIRES gridDim.y == 64). FETCH 288->82MB.
// v8: counted-vmcnt schedule (round-6 post-mortem: __syncthreads emits
// s_waitcnt vmcnt(0) before s_barrier -> prefetch distance ZERO).
// v9 hardening (round-7 hang post-mortem): raw s_barrier is NOT a compiler
// memory fence -- ds_reads could hoist above it and read rows staged by
// OTHER waves before their loads land. Pin with sched_barrier(0) after
// EVERY raw barrier (rule #18). Protocol per step:
//   vmcnt(4); s_barrier; SGB        <- tile t published, t+1 in flight
//   ds_read frags
//   lgkmcnt(0); SGB; s_barrier; SGB <- all waves done reading buf[cur]
//   stage(t+2 -> buf[cur]); MFMA    <- loads fly for 2 compute phases
// Last iteration peeled with vmcnt(0). No vmcnt(0) in steady state.
// EPI 0: fused QKV epilogue (N=3072): n<1024 -> Q headed *scale,
//        <2048 -> K headed, else V^T [b,h,kc,t]
// EPI 2: fp32 row-major, + bias + resid
// EPI 3: bf16 row-major, relu(+bias)
template <int EPI>
__global__ __launch_bounds__(256) void gemm_mfma(
    const short* __restrict__ A, const short* __restrict__ Bt,
    const float* __restrict__ bias, const float* __restrict__ resid,
    float* __restrict__ Cf, short* __restrict__ Cb0,
    short* __restrict__ Cb1, short* __restrict__ Cb2,
    int M, int N, int K, float scale)
{
    __shared__ short As[2][128 * 32];
    __shared__ short Bs[2][128 * 32];
    const int tid  = threadIdx.x;
    const int lane = tid & 63, wave = tid >> 6;
    const int quad = lane >> 4, l16 = lane & 15;

    // XCD-grouped remap: lin%8 = XCD under round-robin dispatch.
    // XCD owns m-rows [xcd*8, xcd*8+8) x all n. (gridDim.y == 64.)
    const int lin = blockIdx.y * gridDim.x + blockIdx.x;
    const int xcd = lin & 7;
    const int s   = lin >> 3;
    const int my  = xcd * 8 + (s & 7);   // m-row within 64
    const int nx  = s >> 3;              // n-col 0..gridDim.x-1
    const int m0 = my * 128, n0 = nx * 128;

    const int wm = (wave >> 1) * 64, wn = (wave & 1) * 64;

    f32x4 acc[4][4];
#pragma unroll
    for (int i = 0; i < 4; ++i)
#pragma unroll
        for (int j = 0; j < 4; ++j) acc[i][j] = f32x4{0.f, 0.f, 0.f, 0.f};

    const short* gA = A  + (size_t)(m0 + wave * 32 + (lane >> 2)) * K + (lane & 3) * 8;
    const short* gB = Bt + (size_t)(n0 + wave * 32 + (lane >> 2)) * K + (lane & 3) * 8;
    const size_t rstep = (size_t)16 * K;
    const int woff = wave * 1024;

    auto stageg = [&](int buf) {
        async_copy16(gA,         &As[buf][woff]);
        async_copy16(gA + rstep, &As[buf][woff + 512]);
        async_copy16(gB,         &Bs[buf][woff]);
        async_copy16(gB + rstep, &Bs[buf][woff + 512]);
        gA += 32; gB += 32;
    };

    stageg(0);           // tile 0 -> buf 0   (4 loads in flight)
    stageg(1);           // tile 1 -> buf 1   (8 in flight)

    const int ntile = K >> 5;
    int cur = 0;
    for (int t = 0; t < ntile; ++t) {
        if (t + 1 < ntile) asm volatile("s_waitcnt vmcnt(4)" ::: "memory");
        else               asm volatile("s_waitcnt vmcnt(0)" ::: "memory");
        __builtin_amdgcn_s_barrier();
        __builtin_amdgcn_sched_barrier(0);   // pin ds_reads below barrier

        bf16x8 af[4], bfr[4];
#pragma unroll
        for (int mt = 0; mt < 4; ++mt)
            af[mt] = *(const bf16x8*)(&As[cur][(wm + mt * 16 + l16) * 32 + quad * 8]);
#pragma unroll
        for (int nt2 = 0; nt2 < 4; ++nt2)
            bfr[nt2] = *(const bf16x8*)(&Bs[cur][(wn + nt2 * 16 + l16) * 32 + quad * 8]);

        if (t + 2 < ntile) {
            asm volatile("s_waitcnt lgkmcnt(0)" ::: "memory");
            __builtin_amdgcn_sched_barrier(0);
            __builtin_amdgcn_s_barrier();        // all waves done reading cur
            __builtin_amdgcn_sched_barrier(0);   // pin stage below barrier
            stageg(cur);                         // tile t+2 -> buf[cur]
        }

#pragma unroll
        for (int mt = 0; mt < 4; ++mt)
#pragma unroll
            for (int nt2 = 0; nt2 < 4; ++nt2)
                acc[mt][nt2] = __builtin_amdgcn_mfma_f32_16x16x32_bf16(
                    af[mt], bfr[nt2], acc[mt][nt2], 0, 0, 0);
        cur ^= 1;
    }

#pragma unroll
    for (int mt = 0; mt < 4; ++mt) {
#pragma unroll
        for (int nt2 = 0; nt2 < 4; ++nt2) {
#pragma unroll
            for (int r = 0; r < 4; ++r) {
                const int m = m0 + wm + mt * 16 + quad * 4 + r;
                const int c = n0 + wn + nt2 * 16 + l16;
                float val = acc[mt][nt2][r];
                if (EPI == 0) {
                    const int sel = c >> 10, cl = c & 1023;
                    if (sel == 0)
                        Cb0[headed_idx(m, cl)] = f2bf(val * scale);
                    else if (sel == 1)
                        Cb1[headed_idx(m, cl)] = f2bf(val);
                    else {
                        int b = m >> 11, t = m & 2047;
                        size_t idx = ((((size_t)((b << 4) | (cl >> 6)) << 6) | (cl & 63)) << 11) | t;
                        Cb2[idx] = f2bf(val);
                    }
                } else if (EPI == 2) {
                    size_t idx = (size_t)m * N + c;
                    Cf[idx] = val + bias[c] + resid[idx];
                } else {  // EPI 3
                    float v2 = val + bias[c];
                    Cb0[(size_t)m * N + c] = f2bf(v2 > 0.f ? v2 : 0.f);
                }
            }
        }
    }
}

// ---------------- narrow-N bf16 MFMA GEMM (128x64 tile, BK=64) -------------
// v6: for the two N=1024 GEMMs (proj, FFN2): grid (16,64) = 1024 blocks.
// LDS [row][64] rows XOR-swizzled (g^(row&7)) via pre-swizzled global
// source + linear LDS dest -> 0 bank conflicts (round-5 PMC).
// v8/v9: counted-vmcnt schedule + sched_barrier pinning (see gemm_mfma).
// L=6 loads/stage. LDS 48KB -> 3 blocks/CU.
// Epilogue = fp32 row-major, + bias + resid. REQUIRES grid (16,64).
__global__ __launch_bounds__(256) void gemm_n64(
    const short* __restrict__ A, const short* __restrict__ Bt,
    const float* __restrict__ bias, const float* __restrict__ resid,
    float* __restrict__ Cf, int M, int N, int K)
{
    __shared__ short As[2][128 * 64];   // 2 x 16 KB
    __shared__ short Bs[2][64 * 64];    // 2 x 8 KB
    const int tid  = threadIdx.x;
    const int lane = tid & 63, wave = tid >> 6;
    const int quad = lane >> 4, l16 = lane & 15;

    const int lin = blockIdx.y * 16 + blockIdx.x;   // grid (16,64)
    const int xcd = lin & 7;
    const int s   = lin >> 3;                       // 0..127
    const int m0  = (xcd * 8 + (s & 7)) * 128;
    const int n0  = (s >> 3) * 64;

    const int wm = (wave >> 1) * 64, wn = (wave & 1) * 32;

    f32x4 acc[4][2];
#pragma unroll
    for (int i = 0; i < 4; ++i)
#pragma unroll
        for (int j = 0; j < 2; ++j) acc[i][j] = f32x4{0.f, 0.f, 0.f, 0.f};

    // staging: A 128x64 shorts = 1024 granules (4/thread), B 64x64 = 512
    // (2/thread). slot sl: row = sl>>3, LDS pos = sl&7, source granule
    // (sl&7)^(row&7) so reads can XOR the same way.
    const short* gA[4];
    const short* gB[2];
    int dA[4], dB[2];
#pragma unroll
    for (int i = 0; i < 4; ++i) {
        const int sl = tid + 256 * i, r = sl >> 3, g = (sl & 7) ^ (r & 7);
        gA[i] = A + (size_t)(m0 + r) * K + g * 8;
        dA[i] = sl * 8;
    }
#pragma unroll
    for (int i = 0; i < 2; ++i) {
        const int sl = tid + 256 * i, r = sl >> 3, g = (sl & 7) ^ (r & 7);
        gB[i] = Bt + (size_t)(n0 + r) * K + g * 8;
        dB[i] = sl * 8;
    }

    auto stageg = [&](int buf) {
#pragma unroll
        for (int i = 0; i < 4; ++i) { async_copy16(gA[i], &As[buf][dA[i]]); gA[i] += 64; }
#pragma unroll
        for (int i = 0; i < 2; ++i) { async_copy16(gB[i], &Bs[buf][dB[i]]); gB[i] += 64; }
    };

    stageg(0);           // tile 0 -> buf 0   (6 loads in flight)
    stageg(1);           // tile 1 -> buf 1   (12 in flight)

    const int ntile = K >> 6;
    int cur = 0;
    for (int t = 0; t < ntile; ++t) {
        if (t + 1 < ntile) asm volatile("s_waitcnt vmcnt(6)" ::: "memory");
        else               asm volatile("s_waitcnt vmcnt(0)" ::: "memory");
        __builtin_amdgcn_s_barrier();
        __builtin_amdgcn_sched_barrier(0);   // pin ds_reads below barrier

        bf16x8 af[4][2], bfr[2][2];
#pragma unroll
        for (int mt = 0; mt < 4; ++mt) {
            const int r = wm + mt * 16 + l16;
            af[mt][0] = *(const bf16x8*)(&As[cur][r * 64 + (((quad    ) ^ (r & 7)) << 3)]);
            af[mt][1] = *(const bf16x8*)(&As[cur][r * 64 + (((quad + 4) ^ (r & 7)) << 3)]);
        }
#pragma unroll
        for (int nt2 = 0; nt2 < 2; ++nt2) {
            const int r = wn + nt2 * 16 + l16;
            bfr[nt2][0] = *(const bf16x8*)(&Bs[cur][r * 64 + (((quad    ) ^ (r & 7)) << 3)]);
            bfr[nt2][1] = *(const bf16x8*)(&Bs[cur][r * 64 + (((quad + 4) ^ (r & 7)) << 3)]);
        }

        if (t + 2 < ntile) {
            asm volatile("s_waitcnt lgkmcnt(0)" ::: "memory");
            __builtin_amdgcn_sched_barrier(0);
            __builtin_amdgcn_s_barrier();        // all waves done reading cur
            __builtin_amdgcn_sched_barrier(0);   // pin stage below barrier
            stageg(cur);                         // tile t+2 -> buf[cur]
        }

#pragma unroll
        for (int mt = 0; mt < 4; ++mt)
#pragma unroll
            for (int nt2 = 0; nt2 < 2; ++nt2) {
                acc[mt][nt2] = __builtin_amdgcn_mfma_f32_16x16x32_bf16(
                    af[mt][0], bfr[nt2][0], acc[mt][nt2], 0, 0, 0);
                acc[mt][nt2] = __builtin_amdgcn_mfma_f32_16x16x32_bf16(
                    af[mt][1], bfr[nt2][1], acc[mt][nt2], 0, 0, 0);
            }
        cur ^= 1;
    }

#pragma unroll
    for (int mt = 0; mt < 4; ++mt) {
#pragma unroll
        for (int nt2 = 0; nt2 < 2; ++nt2) {
#pragma unroll
            for (int r = 0; r < 4; ++r) {
                const int m = m0 + wm + mt * 16 + quad * 4 + r;
                const int c = n0 + wn + nt2 * 16 + l16;
                const size_t idx = (size_t)m * N + c;
                Cf[idx] = acc[mt][nt2][r] + bias[c] + resid[idx];
            }
        }
    }
}

// ---------------- MFMA flash attention, LDS-staged K/V ---------------------
// v4 (round-6 passing version, unchanged): tile-pair balance, XCD
// clustering, 40KB LDS, 4 blocks/CU, __syncthreads-based 2-phase pipeline.
// S^T = K Q^T (A=K-frag, B=Q-frag) so each lane owns ONE query row (l16):
//   - P packed via v_perm -> ds_write_b64 (4 writes/chunk, XOR-swizzled)
//   - row-sum l is a per-lane scalar (2 shfls per tile at the end)
// PV computes O^T (A=V^T-frag, B=P from LDS). No-max softmax via exp2
// (Q pre-scaled by HD^-0.5 * log2 e). Output bf16 row-major (head concat).
__global__ __launch_bounds__(256, 4) void fattn_kernel(
    const short* __restrict__ Q,
    const short* __restrict__ K,
    const short* __restrict__ VT,
    short* __restrict__ O)
{
    __shared__ short Kl[2][64 * 64];
    __shared__ short Vl[2][64 * 64];
    __shared__ short p_lds[4][16 * 64];
    const int tid  = threadIdx.x;
    const int lane = tid & 63, wave = tid >> 6;
    const int quad = lane >> 4, l16 = lane & 15;

    // XCD-clustered remap (bijective): lin%8 = XCD under round-robin
    // dispatch; all 16 tile-pair blocks of one bh share one XCD.
    const int lin  = blockIdx.y * 16 + blockIdx.x;   // 0..1023
    const int xcd  = lin & 7;
    const int slot = lin >> 3;                       // 0..127
    const int bh   = xcd * 8 + (slot >> 4);          // 0..63
    const int px   = slot & 15;                      // 0..15
    const int tiles[2] = { 31 - px, px };            // heavy tile first

    const int bb = bh >> 4, hh = bh & 15;
    const size_t bhoff = (size_t)bh * (Tsz * HDs);
    const short* Qb = Q + bhoff;
    const short* Kb = K + bhoff;
    const short* Vb = VT + bhoff;

    // staging: 512 slots of 16B per 64x64 tile, 2 rounds of 256 threads.
    // slot s: row = s>>3, granule = s&7; fetch source granule (s&7)^(row&7)
    const int s_a = tid, s_b = tid + 256;
    const int ra = s_a >> 3, ga = (s_a & 7) ^ (ra & 7);
    const int rb = s_b >> 3, gb = (s_b & 7) ^ (rb & 7);

    short* pw = &p_lds[wave][0];
    // swizzled read offsets (shorts): granule g stored at g^(l16&7)
    const int rd0 = l16 * 64 + (((quad    ) ^ (l16 & 7)) << 3);
    const int rd1 = l16 * 64 + (((quad + 4) ^ (l16 & 7)) << 3);

    // Q B-fragments for both tiles upfront: lane n = query row l16, k = d
    bf16x8 bq[2][2];
#pragma unroll
    for (int ti = 0; ti < 2; ++ti) {
        const short* qp = Qb + (size_t)(tiles[ti] * 64 + wave * 16 + l16) * 64 + quad * 8;
        bq[ti][0] = *(const bf16x8*)qp;
        bq[ti][1] = *(const bf16x8*)(qp + 32);
    }

    auto stage = [&](int c64, int buf) {
        short* kb_l = &Kl[buf][0];
        short* vb_l = &Vl[buf][0];
        async_copy16(Kb + (((size_t)(c64 + ra)) << 6) + (ga << 3), kb_l + s_a * 8);
        async_copy16(Kb + (((size_t)(c64 + rb)) << 6) + (gb << 3), kb_l + s_b * 8);
        async_copy16(Vb + ((size_t)ra << 11) + c64 + (ga << 3), vb_l + s_a * 8);
        async_copy16(Vb + ((size_t)rb << 11) + c64 + (gb << 3), vb_l + s_b * 8);
    };

    stage(tiles[0] * 0, 0);     // tile A chunk 0
    __syncthreads();            // compiler drains vmcnt before s_barrier

    int phase = 0;
#pragma unroll
    for (int ti = 0; ti < 2; ++ti) {
        const int tile = tiles[ti];
        const int q0w  = tile * 64 + wave * 16;   // wave's first query row
        const int nch  = tile + 1;

        f32x4 oaccT[4];
        float lacc = 0.f;
#pragma unroll
        for (int nt = 0; nt < 4; ++nt) oaccT[nt] = f32x4{0.f, 0.f, 0.f, 0.f};

        for (int c = 0; c < nch; ++c) {
            const int cur = phase & 1;
            if (c + 1 < nch)   stage((c + 1) * 64, cur ^ 1);
            else if (ti == 0)  stage(0, cur ^ 1);    // tile B chunk 0

            const int s0 = c * 64;
            const short* Kc = &Kl[cur][0];
            const short* Vc = &Vl[cur][0];
            // ---- K / V^T A-fragments from LDS (swizzled, balanced b128) ----
            bf16x8 ak[4][2], av[4][2];
#pragma unroll
            for (int ct = 0; ct < 4; ++ct) {
                const int r = ct * 16 + l16;
                ak[ct][0] = *(const bf16x8*)(Kc + r * 64 + (((quad    ) ^ (r & 7)) << 3));
                ak[ct][1] = *(const bf16x8*)(Kc + r * 64 + (((quad + 4) ^ (r & 7)) << 3));
            }
#pragma unroll
            for (int nt = 0; nt < 4; ++nt) {
                const int r = nt * 16 + l16;
                av[nt][0] = *(const bf16x8*)(Vc + r * 64 + (((quad    ) ^ (r & 7)) << 3));
                av[nt][1] = *(const bf16x8*)(Vc + r * 64 + (((quad + 4) ^ (r & 7)) << 3));
            }
            // ---- S^T = K Q^T : D col = query row (l16), row = key pos ----
            f32x4 sfr[4];
#pragma unroll
            for (int ct = 0; ct < 4; ++ct) {
                f32x4 cc = {0.f, 0.f, 0.f, 0.f};
                cc = __builtin_amdgcn_mfma_f32_16x16x32_bf16(ak[ct][0], bq[ti][0], cc, 0, 0, 0);
                cc = __builtin_amdgcn_mfma_f32_16x16x32_bf16(ak[ct][1], bq[ti][1], cc, 0, 0, 0);
                sfr[ct] = cc;
            }
            // ---- causal mask (only the diagonal chunk) ----
            if (s0 + 63 > q0w) {
                const int qr = q0w + l16;
#pragma unroll
                for (int ct = 0; ct < 4; ++ct)
#pragma unroll
                    for (int r = 0; r < 4; ++r)
                        if (s0 + ct * 16 + quad * 4 + r > qr)
                            sfr[ct][r] = -INFINITY;
            }
            // ---- P = exp2(S); scalar row-sum; packed b64 LDS writes ----
#pragma unroll
            for (int ct = 0; ct < 4; ++ct) {
                float p0 = __builtin_exp2f(sfr[ct][0]);
                float p1 = __builtin_exp2f(sfr[ct][1]);
                float p2 = __builtin_exp2f(sfr[ct][2]);
                float p3 = __builtin_exp2f(sfr[ct][3]);
                lacc += (p0 + p1) + (p2 + p3);
                uint2 pkv;
                pkv.x = pack_bf16(p1, p0);
                pkv.y = pack_bf16(p3, p2);
                const int g = (2 * ct + (quad >> 1)) ^ (l16 & 7);
                *(uint2*)(pw + l16 * 64 + (g << 3) + (quad & 1) * 4) = pkv;
            }
            // ---- P back as B-fragments (balanced b128 reads) ----
            bf16x8 bp0 = *(const bf16x8*)(pw + rd0);
            bf16x8 bp1 = *(const bf16x8*)(pw + rd1);
            // ---- O^T += V^T P^T : D col = query row, row = head dim ----
#pragma unroll
            for (int nt = 0; nt < 4; ++nt) {
                oaccT[nt] = __builtin_amdgcn_mfma_f32_16x16x32_bf16(av[nt][0], bp0, oaccT[nt], 0, 0, 0);
                oaccT[nt] = __builtin_amdgcn_mfma_f32_16x16x32_bf16(av[nt][1], bp1, oaccT[nt], 0, 0, 0);
            }
            __syncthreads();   // next stage drained; all waves done with cur
            ++phase;
        }

        // ---- finalize tile: reduce l across quads, normalize, store ----
        float ps = lacc;
        ps += __shfl_xor(ps, 16);
        ps += __shfl_xor(ps, 32);
        const float inv = 1.f / ps;
        short* orow = O + (size_t)(bb * Tsz + q0w + l16) * Dsz + hh * 64;
#pragma unroll
        for (int nt = 0; nt < 4; ++nt) {
            uint2 pkv;
            pkv.x = pack_bf16(oaccT[nt][1] * inv, oaccT[nt][0] * inv);
            pkv.y = pack_bf16(oaccT[nt][3] * inv, oaccT[nt][2] * inv);
            *(uint2*)(orow + nt * 16 + quad * 4) = pkv;
        }
    }
}

extern "C" void kernel_launch(void* const* d_in, const int* in_sizes, int n_in,
                              void* d_out, int out_size, void* d_ws, size_t ws_size,
                              hipStream_t stream) {
    const float* x   = (const float*)d_in[0];
    const float* Wq  = (const float*)d_in[1];
    const float* Wk  = (const float*)d_in[2];
    const float* Wv  = (const float*)d_in[3];
    const float* Wp  = (const float*)d_in[4];
    const float* bp  = (const float*)d_in[5];
    const float* W1  = (const float*)d_in[6];
    const float* b1  = (const float*)d_in[7];
    const float* W2  = (const float*)d_in[8];
    const float* b2  = (const float*)d_in[9];
    const float* g1  = (const float*)d_in[10];
    const float* be1 = (const float*)d_in[11];
    const float* g2  = (const float*)d_in[12];
    const float* be2 = (const float*)d_in[13];
    float* out = (float*)d_out;
    char*  W   = (char*)d_ws;

    short* h1  = (short*)(W);
    short* ff1 = (short*)(W);
    short* qb  = (short*)(W + (16ull << 20));
    short* kb  = (short*)(W + (32ull << 20));
    short* vtb = (short*)(W + (48ull << 20));
    short* o   = (short*)(W + (64ull << 20));
    short* h2  = (short*)(W + (80ull << 20));
    short* wqt = (short*)(W + (96ull << 20));
    short* wpt = (short*)(W + (102ull << 20));
    short* w1t = (short*)(W + (104ull << 20));
    short* w2t = (short*)(W + (112ull << 20));

    const int M = Bsz * Tsz;  // 8192
    // Q scale folds softmax's HD^-0.5 and exp->exp2 conversion (log2 e).
    const float qscale = 0.125f * 1.44269504f;

    transpose_cvt_qkv<<<dim3(2, 32, 48), 256, 0, stream>>>(Wq, Wk, Wv, wqt);
    transpose_cvt<<<dim3(32, 32, 1),  256, 0, stream>>>(Wp, wpt, 1024, 1024);
    transpose_cvt<<<dim3(128, 32, 1), 256, 0, stream>>>(W1, w1t, 1024, 4096);
    transpose_cvt<<<dim3(32, 128, 1), 256, 0, stream>>>(W2, w2t, 4096, 1024);

    ln_kernel<<<dim3(M), 256, 0, stream>>>(x, g1, be1, h1);

    gemm_mfma<0><<<dim3(24, 64), 256, 0, stream>>>(
        h1, wqt, nullptr, nullptr, nullptr, qb, kb, vtb, M, 3072, 1024, qscale);

    fattn_kernel<<<dim3(16, Bsz * Hn), 256, 0, stream>>>(qb, kb, vtb, o);

    gemm_n64<<<dim3(16, 64), 256, 0, stream>>>(
        o, wpt, bp, x, out, M, 1024, 1024);

    ln_kernel<<<dim3(M), 256, 0, stream>>>(out, g2, be2, h2);

    gemm_mfma<3><<<dim3(32, 64), 256, 0, stream>>>(
        h2, w1t, b1, nullptr, nullptr, ff1, nullptr, nullptr, M, 4096, 1024, 1.f);

    gemm_n64<<<dim3(16, 64), 256, 0, stream>>>(
        ff1, w2t, b2, out, out, M, 1024, 4096);
}

// Round 9
// 512.020 us; speedup vs baseline: 1.0802x; 1.0030x over previous
//
#include <hip/hip_runtime.h>
#include <hip/hip_bf16.h>
#include <math.h>

#define Bsz 4
#define Tsz 2048
#define Dsz 1024
#define Hn  16
#define HDs 64

typedef __attribute__((ext_vector_type(8))) short bf16x8;
typedef __attribute__((ext_vector_type(4))) float f32x4;

typedef const __attribute__((address_space(1))) void gvoid;
typedef __attribute__((address_space(3))) void lvoid;

__device__ __forceinline__ void async_copy16(const short* g, short* l) {
    __builtin_amdgcn_global_load_lds((gvoid*)g, (lvoid*)l, 16, 0, 0);
}

__device__ __forceinline__ short f2bf(float x) {
    __hip_bfloat16 h = __float2bfloat16(x);
    return *reinterpret_cast<short*>(&h);
}

// pack two fp32 -> two bf16 in one u32 (round-half-up via +0x8000, then
// v_perm grabs the high shorts). lo -> low half, hi -> high half.
__device__ __forceinline__ unsigned int pack_bf16(float hi, float lo) {
    unsigned int uh = __float_as_uint(hi) + 0x8000u;
    unsigned int ul = __float_as_uint(lo) + 0x8000u;
    return __builtin_amdgcn_perm(uh, ul, 0x07060302u);
}

// index into [b, h, t, kc] tensor given m = b*T + t, c = h*64 + kc
__device__ __forceinline__ size_t headed_idx(int m, int c) {
    int b = m >> 11, t = m & 2047, h = c >> 6, kc = c & 63;
    return (((size_t)(b * Hn + h) * Tsz + t) << 6) + kc;
}

// ---------------- LayerNorm: fp32 in, bf16 out -----------------------------
__global__ __launch_bounds__(256) void ln_kernel(const float* __restrict__ x,
                                                 const float* __restrict__ g,
                                                 const float* __restrict__ beta,
                                                 short* __restrict__ out)
{
    const int row = blockIdx.x;
    const float* xr = x + (size_t)row * Dsz;
    float v[4];
    float s = 0.f, s2 = 0.f;
#pragma unroll
    for (int i = 0; i < 4; ++i) {
        v[i] = xr[threadIdx.x + 256 * i];
        s += v[i];
        s2 += v[i] * v[i];
    }
#pragma unroll
    for (int off = 32; off; off >>= 1) {
        s  += __shfl_xor(s,  off);
        s2 += __shfl_xor(s2, off);
    }
    __shared__ float red[8];
    const int wave = threadIdx.x >> 6;
    if ((threadIdx.x & 63) == 0) { red[wave * 2] = s; red[wave * 2 + 1] = s2; }
    __syncthreads();
    s  = red[0] + red[2] + red[4] + red[6];
    s2 = red[1] + red[3] + red[5] + red[7];
    const float mu  = s * (1.f / Dsz);
    const float var = s2 * (1.f / Dsz) - mu * mu;
    const float rs  = rsqrtf(var + 1e-5f);
    short* orow = out + (size_t)row * Dsz;
#pragma unroll
    for (int i = 0; i < 4; ++i) {
        int col = threadIdx.x + 256 * i;
        orow[col] = f2bf((v[i] - mu) * rs * g[col] + beta[col]);
    }
}

// ---------------- fp32 [R][C] slice -> bf16 [C][R] (weight prep) -----------
__global__ __launch_bounds__(256) void transpose_cvt(
    const float* __restrict__ in, short* __restrict__ outp, int R, int C)
{
    __shared__ float tile[32][33];
    const int r0 = blockIdx.y * 32, c0 = blockIdx.x * 32;
    const size_t so = (size_t)blockIdx.z * R * C;
    const int tx = threadIdx.x & 31, ty = threadIdx.x >> 5;
    const float* ip = in + so;
    short* op = outp + so;
#pragma unroll
    for (int i = 0; i < 4; ++i)
        tile[ty + i * 8][tx] = ip[(size_t)(r0 + ty + i * 8) * C + c0 + tx];
    __syncthreads();
#pragma unroll
    for (int i = 0; i < 4; ++i)
        op[(size_t)(c0 + ty + i * 8) * R + r0 + tx] = f2bf(tile[tx][ty + i * 8]);
}

// QKV variant: z 0..47 selects Wq/Wk/Wv head slices, outputs contiguous.
__global__ __launch_bounds__(256) void transpose_cvt_qkv(
    const float* __restrict__ Wq, const float* __restrict__ Wk,
    const float* __restrict__ Wv, short* __restrict__ outp)
{
    __shared__ float tile[32][33];
    const int z = blockIdx.z;
    const float* in = (z < 16) ? Wq : (z < 32) ? Wk : Wv;
    const int zz = z & 15;
    const int r0 = blockIdx.y * 32, c0 = blockIdx.x * 32;
    const int tx = threadIdx.x & 31, ty = threadIdx.x >> 5;
    const float* ip = in + (size_t)zz * (1024 * 64);
    short* op = outp + (size_t)z * (1024 * 64);
#pragma unroll
    for (int i = 0; i < 4; ++i)
        tile[ty + i * 8][tx] = ip[(size_t)(r0 + ty + i * 8) * 64 + c0 + tx];
    __syncthreads();
#pragma unroll
    for (int i = 0; i < 4; ++i)
        op[(size_t)(c0 + ty + i * 8) * 1024 + r0 + tx] = f2bf(tile[tx][ty + i * 8]);
}

// ---------------- bf16 MFMA GEMM, counted-vmcnt pipeline -------------------
// C[M][N] = A[M][K] (row-major bf16) * Bt[N][K]^T (bf16).
// 128x128 tile, BK=32, 4 waves each computing 64x64 (4x4 of 16x16x32 MFMA).
// This 64x64-per-wave shape reads 8 b128/16 MFMA = 0.031 B/FLOP from LDS
// (1.5x less than the retired 128x64 gemm_n64) -- LDS read traffic is the
// binding resource (round-8 post-mortem: n64's 0.047 B/FLOP = ~62us of LDS
// time for FFN2 out of 100us measured). Read pattern is bank-uniform
// (8 lanes per 4-bank group = b128 optimum).
// v5: XCD-grouped block remap: each XCD owns 8 consecutive m-rows x all
// n-cols (REQUIRES gridDim.y == 64). FETCH 288->82MB.
// v8: counted-vmcnt schedule (round-6 post-mortem: __syncthreads emits
// s_waitcnt vmcnt(0) before s_barrier -> prefetch distance ZERO).
// v9 hardening (round-7 hang post-mortem): raw s_barrier is NOT a compiler
// memory fence -- pin with sched_barrier(0) after EVERY raw barrier
// (rule #18). Protocol per step:
//   vmcnt(4); s_barrier; SGB        <- tile t published, t+1 in flight
//   ds_read frags
//   lgkmcnt(0); SGB; s_barrier; SGB <- all waves done reading buf[cur]
//   stage(t+2 -> buf[cur]); MFMA    <- loads fly for 2 compute phases
// Last iteration peeled with vmcnt(0). No vmcnt(0) in steady state.
// Verified passing in round 8 on EPI 0/3; round 9 routes EPI 2 (proj,
// FFN2) here as well, retiring gemm_n64.
// EPI 0: fused QKV epilogue (N=3072): n<1024 -> Q headed *scale,
//        <2048 -> K headed, else V^T [b,h,kc,t]
// EPI 2: fp32 row-major, + bias + resid
// EPI 3: bf16 row-major, relu(+bias)
template <int EPI>
__global__ __launch_bounds__(256) void gemm_mfma(
    const short* __restrict__ A, const short* __restrict__ Bt,
    const float* __restrict__ bias, const float* __restrict__ resid,
    float* __restrict__ Cf, short* __restrict__ Cb0,
    short* __restrict__ Cb1, short* __restrict__ Cb2,
    int M, int N, int K, float scale)
{
    __shared__ short As[2][128 * 32];
    __shared__ short Bs[2][128 * 32];
    const int tid  = threadIdx.x;
    const int lane = tid & 63, wave = tid >> 6;
    const int quad = lane >> 4, l16 = lane & 15;

    // XCD-grouped remap: lin%8 = XCD under round-robin dispatch.
    // XCD owns m-rows [xcd*8, xcd*8+8) x all n. (gridDim.y == 64.)
    const int lin = blockIdx.y * gridDim.x + blockIdx.x;
    const int xcd = lin & 7;
    const int s   = lin >> 3;
    const int my  = xcd * 8 + (s & 7);   // m-row within 64
    const int nx  = s >> 3;              // n-col 0..gridDim.x-1
    const int m0 = my * 128, n0 = nx * 128;

    const int wm = (wave >> 1) * 64, wn = (wave & 1) * 64;

    f32x4 acc[4][4];
#pragma unroll
    for (int i = 0; i < 4; ++i)
#pragma unroll
        for (int j = 0; j < 4; ++j) acc[i][j] = f32x4{0.f, 0.f, 0.f, 0.f};

    const short* gA = A  + (size_t)(m0 + wave * 32 + (lane >> 2)) * K + (lane & 3) * 8;
    const short* gB = Bt + (size_t)(n0 + wave * 32 + (lane >> 2)) * K + (lane & 3) * 8;
    const size_t rstep = (size_t)16 * K;
    const int woff = wave * 1024;

    auto stageg = [&](int buf) {
        async_copy16(gA,         &As[buf][woff]);
        async_copy16(gA + rstep, &As[buf][woff + 512]);
        async_copy16(gB,         &Bs[buf][woff]);
        async_copy16(gB + rstep, &Bs[buf][woff + 512]);
        gA += 32; gB += 32;
    };

    stageg(0);           // tile 0 -> buf 0   (4 loads in flight)
    stageg(1);           // tile 1 -> buf 1   (8 in flight)

    const int ntile = K >> 5;
    int cur = 0;
    for (int t = 0; t < ntile; ++t) {
        if (t + 1 < ntile) asm volatile("s_waitcnt vmcnt(4)" ::: "memory");
        else               asm volatile("s_waitcnt vmcnt(0)" ::: "memory");
        __builtin_amdgcn_s_barrier();
        __builtin_amdgcn_sched_barrier(0);   // pin ds_reads below barrier

        bf16x8 af[4], bfr[4];
#pragma unroll
        for (int mt = 0; mt < 4; ++mt)
            af[mt] = *(const bf16x8*)(&As[cur][(wm + mt * 16 + l16) * 32 + quad * 8]);
#pragma unroll
        for (int nt2 = 0; nt2 < 4; ++nt2)
            bfr[nt2] = *(const bf16x8*)(&Bs[cur][(wn + nt2 * 16 + l16) * 32 + quad * 8]);

        if (t + 2 < ntile) {
            asm volatile("s_waitcnt lgkmcnt(0)" ::: "memory");
            __builtin_amdgcn_sched_barrier(0);
            __builtin_amdgcn_s_barrier();        // all waves done reading cur
            __builtin_amdgcn_sched_barrier(0);   // pin stage below barrier
            stageg(cur);                         // tile t+2 -> buf[cur]
        }

#pragma unroll
        for (int mt = 0; mt < 4; ++mt)
#pragma unroll
            for (int nt2 = 0; nt2 < 4; ++nt2)
                acc[mt][nt2] = __builtin_amdgcn_mfma_f32_16x16x32_bf16(
                    af[mt], bfr[nt2], acc[mt][nt2], 0, 0, 0);
        cur ^= 1;
    }

#pragma unroll
    for (int mt = 0; mt < 4; ++mt) {
#pragma unroll
        for (int nt2 = 0; nt2 < 4; ++nt2) {
#pragma unroll
            for (int r = 0; r < 4; ++r) {
                const int m = m0 + wm + mt * 16 + quad * 4 + r;
                const int c = n0 + wn + nt2 * 16 + l16;
                float val = acc[mt][nt2][r];
                if (EPI == 0) {
                    const int sel = c >> 10, cl = c & 1023;
                    if (sel == 0)
                        Cb0[headed_idx(m, cl)] = f2bf(val * scale);
                    else if (sel == 1)
                        Cb1[headed_idx(m, cl)] = f2bf(val);
                    else {
                        int b = m >> 11, t = m & 2047;
                        size_t idx = ((((size_t)((b << 4) | (cl >> 6)) << 6) | (cl & 63)) << 11) | t;
                        Cb2[idx] = f2bf(val);
                    }
                } else if (EPI == 2) {
                    size_t idx = (size_t)m * N + c;
                    Cf[idx] = val + bias[c] + resid[idx];
                } else {  // EPI 3
                    float v2 = val + bias[c];
                    Cb0[(size_t)m * N + c] = f2bf(v2 > 0.f ? v2 : 0.f);
                }
            }
        }
    }
}

// ---------------- MFMA flash attention, LDS-staged K/V ---------------------
// v4 (round-6 passing version, unchanged): tile-pair balance, XCD
// clustering, 40KB LDS, 4 blocks/CU, __syncthreads-based 2-phase pipeline.
// S^T = K Q^T (A=K-frag, B=Q-frag) so each lane owns ONE query row (l16):
//   - P packed via v_perm -> ds_write_b64 (4 writes/chunk, XOR-swizzled)
//   - row-sum l is a per-lane scalar (2 shfls per tile at the end)
// PV computes O^T (A=V^T-frag, B=P from LDS). No-max softmax via exp2
// (Q pre-scaled by HD^-0.5 * log2 e). Output bf16 row-major (head concat).
__global__ __launch_bounds__(256, 4) void fattn_kernel(
    const short* __restrict__ Q,
    const short* __restrict__ K,
    const short* __restrict__ VT,
    short* __restrict__ O)
{
    __shared__ short Kl[2][64 * 64];
    __shared__ short Vl[2][64 * 64];
    __shared__ short p_lds[4][16 * 64];
    const int tid  = threadIdx.x;
    const int lane = tid & 63, wave = tid >> 6;
    const int quad = lane >> 4, l16 = lane & 15;

    // XCD-clustered remap (bijective): lin%8 = XCD under round-robin
    // dispatch; all 16 tile-pair blocks of one bh share one XCD.
    const int lin  = blockIdx.y * 16 + blockIdx.x;   // 0..1023
    const int xcd  = lin & 7;
    const int slot = lin >> 3;                       // 0..127
    const int bh   = xcd * 8 + (slot >> 4);          // 0..63
    const int px   = slot & 15;                      // 0..15
    const int tiles[2] = { 31 - px, px };            // heavy tile first

    const int bb = bh >> 4, hh = bh & 15;
    const size_t bhoff = (size_t)bh * (Tsz * HDs);
    const short* Qb = Q + bhoff;
    const short* Kb = K + bhoff;
    const short* Vb = VT + bhoff;

    // staging: 512 slots of 16B per 64x64 tile, 2 rounds of 256 threads.
    // slot s: row = s>>3, granule = s&7; fetch source granule (s&7)^(row&7)
    const int s_a = tid, s_b = tid + 256;
    const int ra = s_a >> 3, ga = (s_a & 7) ^ (ra & 7);
    const int rb = s_b >> 3, gb = (s_b & 7) ^ (rb & 7);

    short* pw = &p_lds[wave][0];
    // swizzled read offsets (shorts): granule g stored at g^(l16&7)
    const int rd0 = l16 * 64 + (((quad    ) ^ (l16 & 7)) << 3);
    const int rd1 = l16 * 64 + (((quad + 4) ^ (l16 & 7)) << 3);

    // Q B-fragments for both tiles upfront: lane n = query row l16, k = d
    bf16x8 bq[2][2];
#pragma unroll
    for (int ti = 0; ti < 2; ++ti) {
        const short* qp = Qb + (size_t)(tiles[ti] * 64 + wave * 16 + l16) * 64 + quad * 8;
        bq[ti][0] = *(const bf16x8*)qp;
        bq[ti][1] = *(const bf16x8*)(qp + 32);
    }

    auto stage = [&](int c64, int buf) {
        short* kb_l = &Kl[buf][0];
        short* vb_l = &Vl[buf][0];
        async_copy16(Kb + (((size_t)(c64 + ra)) << 6) + (ga << 3), kb_l + s_a * 8);
        async_copy16(Kb + (((size_t)(c64 + rb)) << 6) + (gb << 3), kb_l + s_b * 8);
        async_copy16(Vb + ((size_t)ra << 11) + c64 + (ga << 3), vb_l + s_a * 8);
        async_copy16(Vb + ((size_t)rb << 11) + c64 + (gb << 3), vb_l + s_b * 8);
    };

    stage(tiles[0] * 0, 0);     // tile A chunk 0
    __syncthreads();            // compiler drains vmcnt before s_barrier

    int phase = 0;
#pragma unroll
    for (int ti = 0; ti < 2; ++ti) {
        const int tile = tiles[ti];
        const int q0w  = tile * 64 + wave * 16;   // wave's first query row
        const int nch  = tile + 1;

        f32x4 oaccT[4];
        float lacc = 0.f;
#pragma unroll
        for (int nt = 0; nt < 4; ++nt) oaccT[nt] = f32x4{0.f, 0.f, 0.f, 0.f};

        for (int c = 0; c < nch; ++c) {
            const int cur = phase & 1;
            if (c + 1 < nch)   stage((c + 1) * 64, cur ^ 1);
            else if (ti == 0)  stage(0, cur ^ 1);    // tile B chunk 0

            const int s0 = c * 64;
            const short* Kc = &Kl[cur][0];
            const short* Vc = &Vl[cur][0];
            // ---- K / V^T A-fragments from LDS (swizzled, balanced b128) ----
            bf16x8 ak[4][2], av[4][2];
#pragma unroll
            for (int ct = 0; ct < 4; ++ct) {
                const int r = ct * 16 + l16;
                ak[ct][0] = *(const bf16x8*)(Kc + r * 64 + (((quad    ) ^ (r & 7)) << 3));
                ak[ct][1] = *(const bf16x8*)(Kc + r * 64 + (((quad + 4) ^ (r & 7)) << 3));
            }
#pragma unroll
            for (int nt = 0; nt < 4; ++nt) {
                const int r = nt * 16 + l16;
                av[nt][0] = *(const bf16x8*)(Vc + r * 64 + (((quad    ) ^ (r & 7)) << 3));
                av[nt][1] = *(const bf16x8*)(Vc + r * 64 + (((quad + 4) ^ (r & 7)) << 3));
            }
            // ---- S^T = K Q^T : D col = query row (l16), row = key pos ----
            f32x4 sfr[4];
#pragma unroll
            for (int ct = 0; ct < 4; ++ct) {
                f32x4 cc = {0.f, 0.f, 0.f, 0.f};
                cc = __builtin_amdgcn_mfma_f32_16x16x32_bf16(ak[ct][0], bq[ti][0], cc, 0, 0, 0);
                cc = __builtin_amdgcn_mfma_f32_16x16x32_bf16(ak[ct][1], bq[ti][1], cc, 0, 0, 0);
                sfr[ct] = cc;
            }
            // ---- causal mask (only the diagonal chunk) ----
            if (s0 + 63 > q0w) {
                const int qr = q0w + l16;
#pragma unroll
                for (int ct = 0; ct < 4; ++ct)
#pragma unroll
                    for (int r = 0; r < 4; ++r)
                        if (s0 + ct * 16 + quad * 4 + r > qr)
                            sfr[ct][r] = -INFINITY;
            }
            // ---- P = exp2(S); scalar row-sum; packed b64 LDS writes ----
#pragma unroll
            for (int ct = 0; ct < 4; ++ct) {
                float p0 = __builtin_exp2f(sfr[ct][0]);
                float p1 = __builtin_exp2f(sfr[ct][1]);
                float p2 = __builtin_exp2f(sfr[ct][2]);
                float p3 = __builtin_exp2f(sfr[ct][3]);
                lacc += (p0 + p1) + (p2 + p3);
                uint2 pkv;
                pkv.x = pack_bf16(p1, p0);
                pkv.y = pack_bf16(p3, p2);
                const int g = (2 * ct + (quad >> 1)) ^ (l16 & 7);
                *(uint2*)(pw + l16 * 64 + (g << 3) + (quad & 1) * 4) = pkv;
            }
            // ---- P back as B-fragments (balanced b128 reads) ----
            bf16x8 bp0 = *(const bf16x8*)(pw + rd0);
            bf16x8 bp1 = *(const bf16x8*)(pw + rd1);
            // ---- O^T += V^T P^T : D col = query row, row = head dim ----
#pragma unroll
            for (int nt = 0; nt < 4; ++nt) {
                oaccT[nt] = __builtin_amdgcn_mfma_f32_16x16x32_bf16(av[nt][0], bp0, oaccT[nt], 0, 0, 0);
                oaccT[nt] = __builtin_amdgcn_mfma_f32_16x16x32_bf16(av[nt][1], bp1, oaccT[nt], 0, 0, 0);
            }
            __syncthreads();   // next stage drained; all waves done with cur
            ++phase;
        }

        // ---- finalize tile: reduce l across quads, normalize, store ----
        float ps = lacc;
        ps += __shfl_xor(ps, 16);
        ps += __shfl_xor(ps, 32);
        const float inv = 1.f / ps;
        short* orow = O + (size_t)(bb * Tsz + q0w + l16) * Dsz + hh * 64;
#pragma unroll
        for (int nt = 0; nt < 4; ++nt) {
            uint2 pkv;
            pkv.x = pack_bf16(oaccT[nt][1] * inv, oaccT[nt][0] * inv);
            pkv.y = pack_bf16(oaccT[nt][3] * inv, oaccT[nt][2] * inv);
            *(uint2*)(orow + nt * 16 + quad * 4) = pkv;
        }
    }
}

extern "C" void kernel_launch(void* const* d_in, const int* in_sizes, int n_in,
                              void* d_out, int out_size, void* d_ws, size_t ws_size,
                              hipStream_t stream) {
    const float* x   = (const float*)d_in[0];
    const float* Wq  = (const float*)d_in[1];
    const float* Wk  = (const float*)d_in[2];
    const float* Wv  = (const float*)d_in[3];
    const float* Wp  = (const float*)d_in[4];
    const float* bp  = (const float*)d_in[5];
    const float* W1  = (const float*)d_in[6];
    const float* b1  = (const float*)d_in[7];
    const float* W2  = (const float*)d_in[8];
    const float* b2  = (const float*)d_in[9];
    const float* g1  = (const float*)d_in[10];
    const float* be1 = (const float*)d_in[11];
    const float* g2  = (const float*)d_in[12];
    const float* be2 = (const float*)d_in[13];
    float* out = (float*)d_out;
    char*  W   = (char*)d_ws;

    short* h1  = (short*)(W);
    short* ff1 = (short*)(W);
    short* qb  = (short*)(W + (16ull << 20));
    short* kb  = (short*)(W + (32ull << 20));
    short* vtb = (short*)(W + (48ull << 20));
    short* o   = (short*)(W + (64ull << 20));
    short* h2  = (short*)(W + (80ull << 20));
    short* wqt = (short*)(W + (96ull << 20));
    short* wpt = (short*)(W + (102ull << 20));
    short* w1t = (short*)(W + (104ull << 20));
    short* w2t = (short*)(W + (112ull << 20));

    const int M = Bsz * Tsz;  // 8192
    // Q scale folds softmax's HD^-0.5 and exp->exp2 conversion (log2 e).
    const float qscale = 0.125f * 1.44269504f;

    transpose_cvt_qkv<<<dim3(2, 32, 48), 256, 0, stream>>>(Wq, Wk, Wv, wqt);
    transpose_cvt<<<dim3(32, 32, 1),  256, 0, stream>>>(Wp, wpt, 1024, 1024);
    transpose_cvt<<<dim3(128, 32, 1), 256, 0, stream>>>(W1, w1t, 1024, 4096);
    transpose_cvt<<<dim3(32, 128, 1), 256, 0, stream>>>(W2, w2t, 4096, 1024);

    ln_kernel<<<dim3(M), 256, 0, stream>>>(x, g1, be1, h1);

    gemm_mfma<0><<<dim3(24, 64), 256, 0, stream>>>(
        h1, wqt, nullptr, nullptr, nullptr, qb, kb, vtb, M, 3072, 1024, qscale);

    fattn_kernel<<<dim3(16, Bsz * Hn), 256, 0, stream>>>(qb, kb, vtb, o);

    gemm_mfma<2><<<dim3(8, 64), 256, 0, stream>>>(
        o, wpt, bp, x, out, nullptr, nullptr, nullptr, M, 1024, 1024, 1.f);

    ln_kernel<<<dim3(M), 256, 0, stream>>>(out, g2, be2, h2);

    gemm_mfma<3><<<dim3(32, 64), 256, 0, stream>>>(
        h2, w1t, b1, nullptr, nullptr, ff1, nullptr, nullptr, M, 4096, 1024, 1.f);

    gemm_mfma<2><<<dim3(8, 64), 256, 0, stream>>>(
        ff1, w2t, b2, out, out, nullptr, nullptr, nullptr, M, 1024, 4096, 1.f);
}

// Round 10
// 492.948 us; speedup vs baseline: 1.1220x; 1.0387x over previous
//
#include <hip/hip_runtime.h>
#include <hip/hip_bf16.h>
#include <math.h>

#define Bsz 4
#define Tsz 2048
#define Dsz 1024
#define Hn  16
#define HDs 64

typedef __attribute__((ext_vector_type(8))) short bf16x8;
typedef __attribute__((ext_vector_type(4))) float f32x4;

typedef const __attribute__((address_space(1))) void gvoid;
typedef __attribute__((address_space(3))) void lvoid;

__device__ __forceinline__ void async_copy16(const short* g, short* l) {
    __builtin_amdgcn_global_load_lds((gvoid*)g, (lvoid*)l, 16, 0, 0);
}

__device__ __forceinline__ short f2bf(float x) {
    __hip_bfloat16 h = __float2bfloat16(x);
    return *reinterpret_cast<short*>(&h);
}

// pack two fp32 -> two bf16 in one u32 (round-half-up via +0x8000, then
// v_perm grabs the high shorts). lo -> low half, hi -> high half.
__device__ __forceinline__ unsigned int pack_bf16(float hi, float lo) {
    unsigned int uh = __float_as_uint(hi) + 0x8000u;
    unsigned int ul = __float_as_uint(lo) + 0x8000u;
    return __builtin_amdgcn_perm(uh, ul, 0x07060302u);
}

// index into [b, h, t, kc] tensor given m = b*T + t, c = h*64 + kc
__device__ __forceinline__ size_t headed_idx(int m, int c) {
    int b = m >> 11, t = m & 2047, h = c >> 6, kc = c & 63;
    return (((size_t)(b * Hn + h) * Tsz + t) << 6) + kc;
}

// ---------------- LayerNorm: fp32 in, bf16 out -----------------------------
__global__ __launch_bounds__(256) void ln_kernel(const float* __restrict__ x,
                                                 const float* __restrict__ g,
                                                 const float* __restrict__ beta,
                                                 short* __restrict__ out)
{
    const int row = blockIdx.x;
    const float* xr = x + (size_t)row * Dsz;
    float v[4];
    float s = 0.f, s2 = 0.f;
#pragma unroll
    for (int i = 0; i < 4; ++i) {
        v[i] = xr[threadIdx.x + 256 * i];
        s += v[i];
        s2 += v[i] * v[i];
    }
#pragma unroll
    for (int off = 32; off; off >>= 1) {
        s  += __shfl_xor(s,  off);
        s2 += __shfl_xor(s2, off);
    }
    __shared__ float red[8];
    const int wave = threadIdx.x >> 6;
    if ((threadIdx.x & 63) == 0) { red[wave * 2] = s; red[wave * 2 + 1] = s2; }
    __syncthreads();
    s  = red[0] + red[2] + red[4] + red[6];
    s2 = red[1] + red[3] + red[5] + red[7];
    const float mu  = s * (1.f / Dsz);
    const float var = s2 * (1.f / Dsz) - mu * mu;
    const float rs  = rsqrtf(var + 1e-5f);
    short* orow = out + (size_t)row * Dsz;
#pragma unroll
    for (int i = 0; i < 4; ++i) {
        int col = threadIdx.x + 256 * i;
        orow[col] = f2bf((v[i] - mu) * rs * g[col] + beta[col]);
    }
}

// ---------------- fp32 [R][C] slice -> bf16 [C][R] (weight prep) -----------
__global__ __launch_bounds__(256) void transpose_cvt(
    const float* __restrict__ in, short* __restrict__ outp, int R, int C)
{
    __shared__ float tile[32][33];
    const int r0 = blockIdx.y * 32, c0 = blockIdx.x * 32;
    const size_t so = (size_t)blockIdx.z * R * C;
    const int tx = threadIdx.x & 31, ty = threadIdx.x >> 5;
    const float* ip = in + so;
    short* op = outp + so;
#pragma unroll
    for (int i = 0; i < 4; ++i)
        tile[ty + i * 8][tx] = ip[(size_t)(r0 + ty + i * 8) * C + c0 + tx];
    __syncthreads();
#pragma unroll
    for (int i = 0; i < 4; ++i)
        op[(size_t)(c0 + ty + i * 8) * R + r0 + tx] = f2bf(tile[tx][ty + i * 8]);
}

// QKV variant: z 0..47 selects Wq/Wk/Wv head slices, outputs contiguous.
__global__ __launch_bounds__(256) void transpose_cvt_qkv(
    const float* __restrict__ Wq, const float* __restrict__ Wk,
    const float* __restrict__ Wv, short* __restrict__ outp)
{
    __shared__ float tile[32][33];
    const int z = blockIdx.z;
    const float* in = (z < 16) ? Wq : (z < 32) ? Wk : Wv;
    const int zz = z & 15;
    const int r0 = blockIdx.y * 32, c0 = blockIdx.x * 32;
    const int tx = threadIdx.x & 31, ty = threadIdx.x >> 5;
    const float* ip = in + (size_t)zz * (1024 * 64);
    short* op = outp + (size_t)z * (1024 * 64);
#pragma unroll
    for (int i = 0; i < 4; ++i)
        tile[ty + i * 8][tx] = ip[(size_t)(r0 + ty + i * 8) * 64 + c0 + tx];
    __syncthreads();
#pragma unroll
    for (int i = 0; i < 4; ++i)
        op[(size_t)(c0 + ty + i * 8) * 1024 + r0 + tx] = f2bf(tile[tx][ty + i * 8]);
}

// ---------------- bf16 MFMA GEMM, counted-vmcnt pipeline -------------------
// C[M][N] = A[M][K] (row-major bf16) * Bt[N][K]^T (bf16).
// 128x128 tile, BK=32, 4 waves each computing 64x64 (4x4 of 16x16x32 MFMA).
// v5: XCD-grouped block remap: each XCD owns 8 consecutive m-rows x all
// n-cols (REQUIRES gridDim.y == 64). FETCH 288->82MB.
// v8/v9: counted-vmcnt schedule + sched_barrier pinning. Per step:
//   vmcnt(4); s_barrier; SGB        <- tile t published, t+1 in flight
//   ds_read frags
//   lgkmcnt(0); SGB; s_barrier; SGB <- all waves done reading buf[cur]
//   stage(t+2 -> buf[cur]); MFMA    <- loads fly for 2 compute phases
// v10: superrow XOR-swizzle (round-9 post-mortem: SQ_LDS_BANK_CONFLICT
// saturated at 2^23 -- the linear [row][32] layout has 64B rows, granule
// position = quad only, so rows R,R+2,.. collide on identical 16B
// positions = ~8-way ds_read_b128 conflict; retired gemm_n64's XOR
// pattern measured 0). Layout: 128B superrow sr = 2 rows; position
// q in 0..7 holds (row 2sr+((q^sr)>>2), granule (q^sr)&3). Staging keeps
// linear LDS dest (global_load_lds = base + lane*16) and pre-swizzles the
// GLOBAL source per lane (rule #21); reads use per-lane-constant offset
//   addr = (R>>1)*64 + ((((R&1)<<2|quad) ^ ((R>>1)&7))<<3).
// All superrows bank-base 0, 8 positions bijective = n64's 0-conflict class.
// EPI 0: fused QKV epilogue (N=3072): n<1024 -> Q headed *scale,
//        <2048 -> K headed, else V^T [b,h,kc,t]
// EPI 2: fp32 row-major, + bias + resid
// EPI 3: bf16 row-major, relu(+bias)
template <int EPI>
__global__ __launch_bounds__(256) void gemm_mfma(
    const short* __restrict__ A, const short* __restrict__ Bt,
    const float* __restrict__ bias, const float* __restrict__ resid,
    float* __restrict__ Cf, short* __restrict__ Cb0,
    short* __restrict__ Cb1, short* __restrict__ Cb2,
    int M, int N, int K, float scale)
{
    __shared__ short As[2][128 * 32];
    __shared__ short Bs[2][128 * 32];
    const int tid  = threadIdx.x;
    const int lane = tid & 63, wave = tid >> 6;
    const int quad = lane >> 4, l16 = lane & 15;

    // XCD-grouped remap: lin%8 = XCD under round-robin dispatch.
    // XCD owns m-rows [xcd*8, xcd*8+8) x all n. (gridDim.y == 64.)
    const int lin = blockIdx.y * gridDim.x + blockIdx.x;
    const int xcd = lin & 7;
    const int s   = lin >> 3;
    const int my  = xcd * 8 + (s & 7);   // m-row within 64
    const int nx  = s >> 3;              // n-col 0..gridDim.x-1
    const int m0 = my * 128, n0 = nx * 128;

    const int wm = (wave >> 1) * 64, wn = (wave & 1) * 64;

    f32x4 acc[4][4];
#pragma unroll
    for (int i = 0; i < 4; ++i)
#pragma unroll
        for (int j = 0; j < 4; ++j) acc[i][j] = f32x4{0.f, 0.f, 0.f, 0.f};

    // v10 staging source swizzle: LDS slot = lane; slot holds superrow
    // sr=lane>>3, pos q=lane&7 -> content row 2sr+((q^sr)>>2), gran (q^sr)&3
    const int ssr = lane >> 3, sv = (lane & 7) ^ ssr;
    const int srow = ssr * 2 + (sv >> 2), sgr = sv & 3;
    const short* gA = A  + (size_t)(m0 + wave * 32 + srow) * K + sgr * 8;
    const short* gB = Bt + (size_t)(n0 + wave * 32 + srow) * K + sgr * 8;
    const size_t rstep = (size_t)16 * K;
    const int woff = wave * 1024;

    // v10 read swizzle: per-lane constant position offset (shorts)
    const int soff = ((((l16 & 1) << 2) | quad) ^ ((l16 >> 1) & 7)) << 3;
    const int rofs = (l16 >> 1) * 64 + soff;

    auto stageg = [&](int buf) {
        async_copy16(gA,         &As[buf][woff]);
        async_copy16(gA + rstep, &As[buf][woff + 512]);
        async_copy16(gB,         &Bs[buf][woff]);
        async_copy16(gB + rstep, &Bs[buf][woff + 512]);
        gA += 32; gB += 32;
    };

    stageg(0);           // tile 0 -> buf 0   (4 loads in flight)
    stageg(1);           // tile 1 -> buf 1   (8 in flight)

    const int ntile = K >> 5;
    int cur = 0;
    for (int t = 0; t < ntile; ++t) {
        if (t + 1 < ntile) asm volatile("s_waitcnt vmcnt(4)" ::: "memory");
        else               asm volatile("s_waitcnt vmcnt(0)" ::: "memory");
        __builtin_amdgcn_s_barrier();
        __builtin_amdgcn_sched_barrier(0);   // pin ds_reads below barrier

        bf16x8 af[4], bfr[4];
#pragma unroll
        for (int mt = 0; mt < 4; ++mt)
            af[mt] = *(const bf16x8*)(&As[cur][(wm + mt * 16) * 32 + rofs]);
#pragma unroll
        for (int nt2 = 0; nt2 < 4; ++nt2)
            bfr[nt2] = *(const bf16x8*)(&Bs[cur][(wn + nt2 * 16) * 32 + rofs]);

        if (t + 2 < ntile) {
            asm volatile("s_waitcnt lgkmcnt(0)" ::: "memory");
            __builtin_amdgcn_sched_barrier(0);
            __builtin_amdgcn_s_barrier();        // all waves done reading cur
            __builtin_amdgcn_sched_barrier(0);   // pin stage below barrier
            stageg(cur);                         // tile t+2 -> buf[cur]
        }

#pragma unroll
        for (int mt = 0; mt < 4; ++mt)
#pragma unroll
            for (int nt2 = 0; nt2 < 4; ++nt2)
                acc[mt][nt2] = __builtin_amdgcn_mfma_f32_16x16x32_bf16(
                    af[mt], bfr[nt2], acc[mt][nt2], 0, 0, 0);
        cur ^= 1;
    }

#pragma unroll
    for (int mt = 0; mt < 4; ++mt) {
#pragma unroll
        for (int nt2 = 0; nt2 < 4; ++nt2) {
#pragma unroll
            for (int r = 0; r < 4; ++r) {
                const int m = m0 + wm + mt * 16 + quad * 4 + r;
                const int c = n0 + wn + nt2 * 16 + l16;
                float val = acc[mt][nt2][r];
                if (EPI == 0) {
                    const int sel = c >> 10, cl = c & 1023;
                    if (sel == 0)
                        Cb0[headed_idx(m, cl)] = f2bf(val * scale);
                    else if (sel == 1)
                        Cb1[headed_idx(m, cl)] = f2bf(val);
                    else {
                        int b = m >> 11, t = m & 2047;
                        size_t idx = ((((size_t)((b << 4) | (cl >> 6)) << 6) | (cl & 63)) << 11) | t;
                        Cb2[idx] = f2bf(val);
                    }
                } else if (EPI == 2) {
                    size_t idx = (size_t)m * N + c;
                    Cf[idx] = val + bias[c] + resid[idx];
                } else {  // EPI 3
                    float v2 = val + bias[c];
                    Cb0[(size_t)m * N + c] = f2bf(v2 > 0.f ? v2 : 0.f);
                }
            }
        }
    }
}

// ---------------- MFMA flash attention, LDS-staged K/V ---------------------
// v4 (round-6 passing version, unchanged): tile-pair balance, XCD
// clustering, 40KB LDS, 4 blocks/CU, __syncthreads-based 2-phase pipeline.
// S^T = K Q^T (A=K-frag, B=Q-frag) so each lane owns ONE query row (l16):
//   - P packed via v_perm -> ds_write_b64 (4 writes/chunk, XOR-swizzled)
//   - row-sum l is a per-lane scalar (2 shfls per tile at the end)
// PV computes O^T (A=V^T-frag, B=P from LDS). No-max softmax via exp2
// (Q pre-scaled by HD^-0.5 * log2 e). Output bf16 row-major (head concat).
__global__ __launch_bounds__(256, 4) void fattn_kernel(
    const short* __restrict__ Q,
    const short* __restrict__ K,
    const short* __restrict__ VT,
    short* __restrict__ O)
{
    __shared__ short Kl[2][64 * 64];
    __shared__ short Vl[2][64 * 64];
    __shared__ short p_lds[4][16 * 64];
    const int tid  = threadIdx.x;
    const int lane = tid & 63, wave = tid >> 6;
    const int quad = lane >> 4, l16 = lane & 15;

    // XCD-clustered remap (bijective): lin%8 = XCD under round-robin
    // dispatch; all 16 tile-pair blocks of one bh share one XCD.
    const int lin  = blockIdx.y * 16 + blockIdx.x;   // 0..1023
    const int xcd  = lin & 7;
    const int slot = lin >> 3;                       // 0..127
    const int bh   = xcd * 8 + (slot >> 4);          // 0..63
    const int px   = slot & 15;                      // 0..15
    const int tiles[2] = { 31 - px, px };            // heavy tile first

    const int bb = bh >> 4, hh = bh & 15;
    const size_t bhoff = (size_t)bh * (Tsz * HDs);
    const short* Qb = Q + bhoff;
    const short* Kb = K + bhoff;
    const short* Vb = VT + bhoff;

    // staging: 512 slots of 16B per 64x64 tile, 2 rounds of 256 threads.
    // slot s: row = s>>3, granule = s&7; fetch source granule (s&7)^(row&7)
    const int s_a = tid, s_b = tid + 256;
    const int ra = s_a >> 3, ga = (s_a & 7) ^ (ra & 7);
    const int rb = s_b >> 3, gb = (s_b & 7) ^ (rb & 7);

    short* pw = &p_lds[wave][0];
    // swizzled read offsets (shorts): granule g stored at g^(l16&7)
    const int rd0 = l16 * 64 + (((quad    ) ^ (l16 & 7)) << 3);
    const int rd1 = l16 * 64 + (((quad + 4) ^ (l16 & 7)) << 3);

    // Q B-fragments for both tiles upfront: lane n = query row l16, k = d
    bf16x8 bq[2][2];
#pragma unroll
    for (int ti = 0; ti < 2; ++ti) {
        const short* qp = Qb + (size_t)(tiles[ti] * 64 + wave * 16 + l16) * 64 + quad * 8;
        bq[ti][0] = *(const bf16x8*)qp;
        bq[ti][1] = *(const bf16x8*)(qp + 32);
    }

    auto stage = [&](int c64, int buf) {
        short* kb_l = &Kl[buf][0];
        short* vb_l = &Vl[buf][0];
        async_copy16(Kb + (((size_t)(c64 + ra)) << 6) + (ga << 3), kb_l + s_a * 8);
        async_copy16(Kb + (((size_t)(c64 + rb)) << 6) + (gb << 3), kb_l + s_b * 8);
        async_copy16(Vb + ((size_t)ra << 11) + c64 + (ga << 3), vb_l + s_a * 8);
        async_copy16(Vb + ((size_t)rb << 11) + c64 + (gb << 3), vb_l + s_b * 8);
    };

    stage(tiles[0] * 0, 0);     // tile A chunk 0
    __syncthreads();            // compiler drains vmcnt before s_barrier

    int phase = 0;
#pragma unroll
    for (int ti = 0; ti < 2; ++ti) {
        const int tile = tiles[ti];
        const int q0w  = tile * 64 + wave * 16;   // wave's first query row
        const int nch  = tile + 1;

        f32x4 oaccT[4];
        float lacc = 0.f;
#pragma unroll
        for (int nt = 0; nt < 4; ++nt) oaccT[nt] = f32x4{0.f, 0.f, 0.f, 0.f};

        for (int c = 0; c < nch; ++c) {
            const int cur = phase & 1;
            if (c + 1 < nch)   stage((c + 1) * 64, cur ^ 1);
            else if (ti == 0)  stage(0, cur ^ 1);    // tile B chunk 0

            const int s0 = c * 64;
            const short* Kc = &Kl[cur][0];
            const short* Vc = &Vl[cur][0];
            // ---- K / V^T A-fragments from LDS (swizzled, balanced b128) ----
            bf16x8 ak[4][2], av[4][2];
#pragma unroll
            for (int ct = 0; ct < 4; ++ct) {
                const int r = ct * 16 + l16;
                ak[ct][0] = *(const bf16x8*)(Kc + r * 64 + (((quad    ) ^ (r & 7)) << 3));
                ak[ct][1] = *(const bf16x8*)(Kc + r * 64 + (((quad + 4) ^ (r & 7)) << 3));
            }
#pragma unroll
            for (int nt = 0; nt < 4; ++nt) {
                const int r = nt * 16 + l16;
                av[nt][0] = *(const bf16x8*)(Vc + r * 64 + (((quad    ) ^ (r & 7)) << 3));
                av[nt][1] = *(const bf16x8*)(Vc + r * 64 + (((quad + 4) ^ (r & 7)) << 3));
            }
            // ---- S^T = K Q^T : D col = query row (l16), row = key pos ----
            f32x4 sfr[4];
#pragma unroll
            for (int ct = 0; ct < 4; ++ct) {
                f32x4 cc = {0.f, 0.f, 0.f, 0.f};
                cc = __builtin_amdgcn_mfma_f32_16x16x32_bf16(ak[ct][0], bq[ti][0], cc, 0, 0, 0);
                cc = __builtin_amdgcn_mfma_f32_16x16x32_bf16(ak[ct][1], bq[ti][1], cc, 0, 0, 0);
                sfr[ct] = cc;
            }
            // ---- causal mask (only the diagonal chunk) ----
            if (s0 + 63 > q0w) {
                const int qr = q0w + l16;
#pragma unroll
                for (int ct = 0; ct < 4; ++ct)
#pragma unroll
                    for (int r = 0; r < 4; ++r)
                        if (s0 + ct * 16 + quad * 4 + r > qr)
                            sfr[ct][r] = -INFINITY;
            }
            // ---- P = exp2(S); scalar row-sum; packed b64 LDS writes ----
#pragma unroll
            for (int ct = 0; ct < 4; ++ct) {
                float p0 = __builtin_exp2f(sfr[ct][0]);
                float p1 = __builtin_exp2f(sfr[ct][1]);
                float p2 = __builtin_exp2f(sfr[ct][2]);
                float p3 = __builtin_exp2f(sfr[ct][3]);
                lacc += (p0 + p1) + (p2 + p3);
                uint2 pkv;
                pkv.x = pack_bf16(p1, p0);
                pkv.y = pack_bf16(p3, p2);
                const int g = (2 * ct + (quad >> 1)) ^ (l16 & 7);
                *(uint2*)(pw + l16 * 64 + (g << 3) + (quad & 1) * 4) = pkv;
            }
            // ---- P back as B-fragments (balanced b128 reads) ----
            bf16x8 bp0 = *(const bf16x8*)(pw + rd0);
            bf16x8 bp1 = *(const bf16x8*)(pw + rd1);
            // ---- O^T += V^T P^T : D col = query row, row = head dim ----
#pragma unroll
            for (int nt = 0; nt < 4; ++nt) {
                oaccT[nt] = __builtin_amdgcn_mfma_f32_16x16x32_bf16(av[nt][0], bp0, oaccT[nt], 0, 0, 0);
                oaccT[nt] = __builtin_amdgcn_mfma_f32_16x16x32_bf16(av[nt][1], bp1, oaccT[nt], 0, 0, 0);
            }
            __syncthreads();   // next stage drained; all waves done with cur
            ++phase;
        }

        // ---- finalize tile: reduce l across quads, normalize, store ----
        float ps = lacc;
        ps += __shfl_xor(ps, 16);
        ps += __shfl_xor(ps, 32);
        const float inv = 1.f / ps;
        short* orow = O + (size_t)(bb * Tsz + q0w + l16) * Dsz + hh * 64;
#pragma unroll
        for (int nt = 0; nt < 4; ++nt) {
            uint2 pkv;
            pkv.x = pack_bf16(oaccT[nt][1] * inv, oaccT[nt][0] * inv);
            pkv.y = pack_bf16(oaccT[nt][3] * inv, oaccT[nt][2] * inv);
            *(uint2*)(orow + nt * 16 + quad * 4) = pkv;
        }
    }
}

extern "C" void kernel_launch(void* const* d_in, const int* in_sizes, int n_in,
                              void* d_out, int out_size, void* d_ws, size_t ws_size,
                              hipStream_t stream) {
    const float* x   = (const float*)d_in[0];
    const float* Wq  = (const float*)d_in[1];
    const float* Wk  = (const float*)d_in[2];
    const float* Wv  = (const float*)d_in[3];
    const float* Wp  = (const float*)d_in[4];
    const float* bp  = (const float*)d_in[5];
    const float* W1  = (const float*)d_in[6];
    const float* b1  = (const float*)d_in[7];
    const float* W2  = (const float*)d_in[8];
    const float* b2  = (const float*)d_in[9];
    const float* g1  = (const float*)d_in[10];
    const float* be1 = (const float*)d_in[11];
    const float* g2  = (const float*)d_in[12];
    const float* be2 = (const float*)d_in[13];
    float* out = (float*)d_out;
    char*  W   = (char*)d_ws;

    short* h1  = (short*)(W);
    short* ff1 = (short*)(W);
    short* qb  = (short*)(W + (16ull << 20));
    short* kb  = (short*)(W + (32ull << 20));
    short* vtb = (short*)(W + (48ull << 20));
    short* o   = (short*)(W + (64ull << 20));
    short* h2  = (short*)(W + (80ull << 20));
    short* wqt = (short*)(W + (96ull << 20));
    short* wpt = (short*)(W + (102ull << 20));
    short* w1t = (short*)(W + (104ull << 20));
    short* w2t = (short*)(W + (112ull << 20));

    const int M = Bsz * Tsz;  // 8192
    // Q scale folds softmax's HD^-0.5 and exp->exp2 conversion (log2 e).
    const float qscale = 0.125f * 1.44269504f;

    transpose_cvt_qkv<<<dim3(2, 32, 48), 256, 0, stream>>>(Wq, Wk, Wv, wqt);
    transpose_cvt<<<dim3(32, 32, 1),  256, 0, stream>>>(Wp, wpt, 1024, 1024);
    transpose_cvt<<<dim3(128, 32, 1), 256, 0, stream>>>(W1, w1t, 1024, 4096);
    transpose_cvt<<<dim3(32, 128, 1), 256, 0, stream>>>(W2, w2t, 4096, 1024);

    ln_kernel<<<dim3(M), 256, 0, stream>>>(x, g1, be1, h1);

    gemm_mfma<0><<<dim3(24, 64), 256, 0, stream>>>(
        h1, wqt, nullptr, nullptr, nullptr, qb, kb, vtb, M, 3072, 1024, qscale);

    fattn_kernel<<<dim3(16, Bsz * Hn), 256, 0, stream>>>(qb, kb, vtb, o);

    gemm_mfma<2><<<dim3(8, 64), 256, 0, stream>>>(
        o, wpt, bp, x, out, nullptr, nullptr, nullptr, M, 1024, 1024, 1.f);

    ln_kernel<<<dim3(M), 256, 0, stream>>>(out, g2, be2, h2);

    gemm_mfma<3><<<dim3(32, 64), 256, 0, stream>>>(
        h2, w1t, b1, nullptr, nullptr, ff1, nullptr, nullptr, M, 4096, 1024, 1.f);

    gemm_mfma<2><<<dim3(8, 64), 256, 0, stream>>>(
        ff1, w2t, b2, out, out, nullptr, nullptr, nullptr, M, 1024, 4096, 1.f);
}